// Round 6
// baseline (1005.778 us; speedup 1.0000x reference)
//
#include <hip/hip_runtime.h>
#include <hip/hip_bf16.h>

typedef __hip_bfloat16 BF;
typedef unsigned short ushort_t;
typedef __attribute__((ext_vector_type(8))) short short8;
typedef __attribute__((ext_vector_type(4))) short short4v;
typedef __attribute__((ext_vector_type(4))) float f32x4;

#define B_N 8
#define L_N 4096

__device__ __forceinline__ float b2f(BF v){ return __bfloat162float(v); }
__device__ __forceinline__ BF f2b(float v){ return __float2bfloat16(v); }
__device__ __forceinline__ float siluf(float x){ return x / (1.0f + __expf(-x)); }
__device__ __forceinline__ short pks(float v){ BF e = f2b(v); return *(short*)&e; }

// load element idx from raw buffer that is fp32 (flagv=1) or bf16 (0); scrub NaN/Inf
__device__ __forceinline__ float load_raw(const void* src, long idx, int fp32)
{
    if (fp32) {
        float v = ((const float*)src)[idx];
        unsigned u = __float_as_uint(v);
        if ((u & 0x7F800000u) == 0x7F800000u) v = 0.f;
        return v;
    } else {
        ushort_t v = ((const ushort_t*)src)[idx];
        if (((v >> 7) & 0xFF) == 0xFF) v = 0;
        unsigned u = ((unsigned)v) << 16;
        return __uint_as_float(u);
    }
}

// -------- dtype detector: count bf16-NaN/Inf exponent patterns ----------
__global__ __launch_bounds__(256) void k_detect(const ushort_t* __restrict__ x,
                                                int* __restrict__ flag)
{
    __shared__ int cnt[256];
    int t = threadIdx.x;
    int c = 0;
    for (int i = t; i < 65536; i += 256) {
        ushort_t v = x[i];
        if (((v >> 7) & 0xFF) == 0xFF) c++;
    }
    cnt[t] = c;
    __syncthreads();
    for (int s = 128; s > 0; s >>= 1) {
        if (t < s) cnt[t] += cnt[t + s];
        __syncthreads();
    }
    if (t == 0) flag[0] = (cnt[0] > 4) ? 1 : 0;  // 1 => source data is fp32
}

// -------- normalize a float input into clean bf16 -----------------------
__global__ __launch_bounds__(256) void k_convert(const void* __restrict__ src,
                                                 BF* __restrict__ dst, int n,
                                                 const int* __restrict__ flag)
{
    int fp32 = flag[0];
    int i = blockIdx.x * 256 + threadIdx.x;
    int stride = gridDim.x * 256;
    for (; i < n; i += stride) dst[i] = f2b(load_raw(src, i, fp32));
}

// -------- convert x (B,512,L) into cat ch512..1023 region per batch -----
__global__ __launch_bounds__(256) void k_convert_x(const void* __restrict__ src,
                                                   BF* __restrict__ cat,
                                                   const int* __restrict__ flag)
{
    int fp32 = flag[0];
    const long PB = (long)512 * L_N;          // 2,097,152 elems per batch
    const long CAT = (long)1280 * L_N;
    long i = (long)blockIdx.x * 256 + threadIdx.x;
    long stride = (long)gridDim.x * 256;
    for (; i < (long)B_N * PB; i += stride) {
        long b = i / PB, j = i - b * PB;
        cat[b * CAT + PB /*ch512 offset = 512*L_N*/ + j] = f2b(load_raw(src, i, fp32));
    }
}

// ---- zero-fill bf16 region ---------------------------------------------
__global__ __launch_bounds__(256) void k_zerobf(BF* __restrict__ p, int n)
{
    int i = blockIdx.x * 256 + threadIdx.x;
    if (i < n) p[i] = f2b(0.f);
}

// ---- matrix transpose+convert: raw in[r][c] -> out[(c+roff)*opitch + r]
__global__ __launch_bounds__(256) void k_tr_mat(const void* __restrict__ in,
                                                BF* __restrict__ out,
                                                int rows, int cols, int opitch, int roff,
                                                const int* __restrict__ flag)
{
    __shared__ BF tile[32][33];
    int fp32 = flag[0];
    int c0 = blockIdx.x * 32, r0 = blockIdx.y * 32;
    int tx = threadIdx.x & 31, ty = threadIdx.x >> 5;
#pragma unroll
    for (int i = 0; i < 4; i++) {
        int r = r0 + ty + i * 8, c = c0 + tx;
        tile[ty + i * 8][tx] = (r < rows && c < cols) ? f2b(load_raw(in, (long)r * cols + c, fp32))
                                                      : f2b(0.f);
    }
    __syncthreads();
#pragma unroll
    for (int i = 0; i < 4; i++) {
        int c = c0 + ty + i * 8, r = r0 + tx;
        if (c < cols && r < rows) out[(long)(c + roff) * opitch + r] = tile[tx][ty + i * 8];
    }
}

// ---- conv weight transpose+convert: raw w[oc][ic][9] -> wt[tap][oc][ic]
__global__ __launch_bounds__(256) void k_tr_w9(const void* __restrict__ w,
                                               BF* __restrict__ wt,
                                               const int* __restrict__ flag)
{
    int fp32 = flag[0];
    int idx = blockIdx.x * 256 + threadIdx.x;      // 65536 = oc*256+ic
    int oc = idx >> 8, ic = idx & 255;
#pragma unroll
    for (int tap = 0; tap < 9; tap++)
        wt[((long)tap * 256 + oc) * 256 + ic] = f2b(load_raw(w, (long)idx * 9 + tap, fp32));
}

// ================= universal MFMA implicit-GEMM conv ====================
// Same geometry as round 5 (ch-major activations, block 128px x 256oc,
// 8 waves 64x64, KC-chunked double-buffered LDS, weight-tap dbuf).
// NEW: raw s_barrier + lgkmcnt(0)-only drain (global loads stay in
// flight across barriers -- hipcc's __syncthreads would vmcnt(0)-drain
// them) and 2-DEEP register staging: at chunk ci, issue load(ci+2) into
// reg-set X, compute(ci), ds_write reg-set Y (chunk ci+1).  The ds_write
// waits on a counted vmcnt (compiler-inserted dep), never vmcnt(0).
// Chunk k lives in LDS buf k&1; reg-set A holds even chunks, B odd.
// modes: 0 = silu->bf16 ch-major | 1 = silu->bf16/fp32 by flag (cv2)
//        2 = qkv epilogue        | 3 = +bias, no act, bf16 ch-major
template<int TAPS, int KC, bool PXM>
__global__ __launch_bounds__(512, 2) void k_mconv(
    const BF* __restrict__ in, long in_bstride, int ipitch, int cin,
    const BF* __restrict__ wT, int ocp,
    const BF* __restrict__ bias, int coutp, int mode,
    BF* __restrict__ outb, float* __restrict__ outf, long out_bstride,
    const int* __restrict__ flag,
    BF* __restrict__ valp, float* __restrict__ offb, float* __restrict__ awb)
{
    constexpr int NROWS = (TAPS == 9) ? 257 : 128;
    constexpr int PITCH = KC + 8;          // 40 / 72 shorts, b128-aligned rows
    constexpr int NKS   = KC / 32;
    __shared__ short ldsA[2][NROWS * PITCH];

    const int t    = threadIdx.x;
    const int lane = t & 63;
    const int wv   = t >> 6;             // 0..7
    const int ln   = lane & 15;
    const int kg   = lane >> 4;          // 0..3
    const int wr   = wv >> 2;            // 0..1  (M half)
    const int wc   = wv & 3;             // 0..3  (N quarter)
    const int px0  = blockIdx.x * 128;
    const int b    = blockIdx.y;
    const int nbase = blockIdx.z * 256 + wc * 64;
    const bool active = (nbase < coutp);
    const BF* inb = in + (long)b * in_bstride;

    // staging geometry
    //  PXM:   128 rows x KC ch: 4 thr/row, 2x16B contiguous each
    //  ch-major TAPS9 (KC=32): icp=t&15 (16 ch-pairs), seg=t>>4 (32 x 8px)
    //  ch-major TAPS1 (KC=64): icp=t&31 (32 ch-pairs), seg=t>>5 (16 x 8px)
    int icp, seg, srow, scol;
    if (PXM)            { srow = t >> 2; scol = (t & 3) * 16; icp = 0; seg = 0; }
    else if (TAPS == 9) { icp = t & 15; seg = t >> 4; srow = 0; scol = 0; }
    else                { icp = t & 31; seg = t >> 5; srow = 0; scol = 0; }
    const int gp0 = (TAPS == 9) ? (px0 - 64 + seg * 8) : (px0 + seg * 8);
    const bool sval = (TAPS != 9) || (gp0 >= 0 && gp0 < L_N);

    if (TAPS == 9) {                      // zero halo row 256 in BOTH buffers
        if (t < 20)            ((unsigned*)&ldsA[0][256 * PITCH])[t] = 0u;
        if (t >= 64 && t < 84) ((unsigned*)&ldsA[1][256 * PITCH])[t - 64] = 0u;
    }

    f32x4 acc[4][4];
#pragma unroll
    for (int mf = 0; mf < 4; mf++)
#pragma unroll
        for (int nf = 0; nf < 4; nf++) {
            f32x4 z = {0.f, 0.f, 0.f, 0.f};
            acc[mf][nf] = z;
        }

    const int nchunks = cin / KC;

    // two register staging sets (A = even chunks, B = odd chunks)
    short8 ra0, ra1, rb0, rb1;

    auto load_core = [&](int c0, short8& q0, short8& q1) {
        if (PXM) {
            const BF* p = inb + (long)(px0 + srow) * ipitch + c0 + scol;
            q0 = *(const short8*)p;
            q1 = *(const short8*)(p + 8);
        } else {
            if (sval) {
                const BF* p0 = inb + (long)(c0 + icp * 2) * L_N + gp0;
                q0 = *(const short8*)p0;
                q1 = *(const short8*)(p0 + L_N);
            }
        }
    };
    auto write_core = [&](int buf, short8& q0, short8& q1) {
        if (PXM) {
            *(short8*)&ldsA[buf][srow * PITCH + scol]     = q0;
            *(short8*)&ldsA[buf][srow * PITCH + scol + 8] = q1;
        } else {
#pragma unroll
            for (int k = 0; k < 8; k++) {
                unsigned pk = sval ? ((unsigned)(ushort_t)q0[k] |
                                     ((unsigned)(ushort_t)q1[k] << 16)) : 0u;
                *(unsigned*)&ldsA[buf][(seg * 8 + k) * PITCH + icp * 2] = pk;
            }
        }
    };

    // weight fragment loader (compile-time ks/tap in unrolled loops)
    auto wload = [&](int c0, int ks, int tap, int nf) -> short8 {
        int oc = nbase + nf * 16 + ln;
        return *(const short8*)(wT + ((long)(tap * ocp + oc) * cin
                                      + c0 + ks * 32 + kg * 8));
    };

    // compute one KC-chunk out of LDS buffer lbuf
    auto compute = [&](int c0, const short* lbuf) {
        short8 bcur[4], bnxt[4];
#pragma unroll
        for (int nf = 0; nf < 4; nf++) bcur[nf] = wload(c0, 0, 0, nf);
#pragma unroll
        for (int ks = 0; ks < NKS; ks++) {
#pragma unroll
            for (int tap = 0; tap < TAPS; ++tap) {
                const int dy = (TAPS == 9) ? (tap / 3 - 1) : 0;
                const int dx = (TAPS == 9) ? (tap % 3 - 1) : 0;
                const bool lastit = (ks == NKS - 1) && (tap == TAPS - 1);
                if (!lastit) {                  // prefetch next tap's weights
                    const int nks  = (tap == TAPS - 1) ? ks + 1 : ks;
                    const int ntap = (tap == TAPS - 1) ? 0 : tap + 1;
#pragma unroll
                    for (int nf = 0; nf < 4; nf++) bnxt[nf] = wload(c0, nks, ntap, nf);
                }
                short8 afr[4];
#pragma unroll
                for (int mf = 0; mf < 4; mf++) {
                    int ml = wr * 64 + mf * 16 + ln;
                    int row;
                    if (TAPS == 9) {
                        int xs = (ml & 63) + dx;
                        row = (xs >= 0 && xs < 64) ? (ml + dy * 64 + dx + 64) : 256;
                    } else {
                        row = ml;
                    }
                    afr[mf] = *(const short8*)&lbuf[row * PITCH + ks * 32 + kg * 8];
                }
#pragma unroll
                for (int mf = 0; mf < 4; mf++)
#pragma unroll
                    for (int nf = 0; nf < 4; nf++)
                        acc[mf][nf] = __builtin_amdgcn_mfma_f32_16x16x32_bf16(
                            afr[mf], bcur[nf], acc[mf][nf], 0, 0, 0);
                if (!lastit) {
#pragma unroll
                    for (int nf = 0; nf < 4; nf++) bcur[nf] = bnxt[nf];
                }
            }
        }
    };

    // barrier that does NOT drain in-flight global loads (raw s_barrier;
    // only LDS ops must be retired for cross-wave visibility)
    auto barrier = [&]() {
        asm volatile("s_waitcnt lgkmcnt(0)" ::: "memory");
        __builtin_amdgcn_s_barrier();
        __builtin_amdgcn_sched_barrier(0);
    };

    // ---- prologue: chunk 0 staged (latency exposed once), chunk 1 issued
    load_core(0, ra0, ra1);
    write_core(0, ra0, ra1);
    if (nchunks > 1) load_core(KC, rb0, rb1);
    barrier();

    // ---- 2-deep pipelined main loop (2 chunks per iteration) ----------
    for (int ci = 0; ci < nchunks; ci += 2) {
        const int c0 = ci * KC;
        // even sub-iter: chunk ci from buf0; stage A <- ci+2; write B(ci+1)->buf1
        if (ci + 2 < nchunks) load_core(c0 + 2 * KC, ra0, ra1);
        __builtin_amdgcn_sched_barrier(0);
        if (active) compute(c0, ldsA[0]);
        if (ci + 1 < nchunks) write_core(1, rb0, rb1);
        barrier();
        if (ci + 1 >= nchunks) break;
        // odd sub-iter: chunk ci+1 from buf1; stage B <- ci+3; write A(ci+2)->buf0
        if (ci + 3 < nchunks) load_core(c0 + 3 * KC, rb0, rb1);
        __builtin_amdgcn_sched_barrier(0);
        if (active) compute(c0 + KC, ldsA[1]);
        if (ci + 2 < nchunks) write_core(0, ra0, ra1);
        barrier();
    }
    if (!active) return;

    // ---------------- epilogue (8B vector stores, ch-major out) ---------
    const int wf = (mode == 1 && flag) ? flag[0] : 0;
#pragma unroll
    for (int mf = 0; mf < 4; mf++) {
        int px = px0 + wr * 64 + mf * 16 + kg * 4;
#pragma unroll
        for (int nf = 0; nf < 4; nf++) {
            int oc = nbase + nf * 16 + ln;
            f32x4 a = acc[mf][nf];
            if (mode == 0 || mode == 1) {
                a.x = siluf(a.x); a.y = siluf(a.y); a.z = siluf(a.z); a.w = siluf(a.w);
                if (wf) {
                    float* dst = outf + (long)b * out_bstride + (long)oc * L_N + px;
                    *(f32x4*)dst = a;
                } else {
                    BF* dst = outb + (long)b * out_bstride + (long)oc * L_N + px;
                    short4v sv;
                    sv.x = pks(a.x); sv.y = pks(a.y); sv.z = pks(a.z); sv.w = pks(a.w);
                    *(short4v*)dst = sv;
                }
            } else if (mode == 3) {
                float bs = b2f(bias[oc]);
                BF* dst = outb + (long)b * out_bstride + (long)oc * L_N + px;
                short4v sv;
                sv.x = pks(a.x + bs); sv.y = pks(a.y + bs);
                sv.z = pks(a.z + bs); sv.w = pks(a.w + bs);
                *(short4v*)dst = sv;
            } else {  // mode 2: qkv
                if (oc >= 352) continue;
                float bs = b2f(bias[oc]);
                a.x += bs; a.y += bs; a.z += bs; a.w += bs;
                if (oc < 256) {
                    int h = oc >> 5, d = oc & 31;
                    BF* vp = valp + ((long)(b * 8 + h) * L_N + px) * 32 + d;
                    vp[0] = f2b(a.x); vp[32] = f2b(a.y); vp[64] = f2b(a.z); vp[96] = f2b(a.w);
                } else if (oc < 320) {
                    float* op = offb + ((long)b * L_N + px) * 64 + (oc - 256);
                    op[0] = a.x; op[64] = a.y; op[128] = a.z; op[192] = a.w;
                } else {
                    float* ap = awb + ((long)b * L_N + px) * 32 + (oc - 320);
                    ap[0] = a.x; ap[32] = a.y; ap[64] = a.z; ap[96] = a.w;
                }
            }
        }
    }
}

// ---------------- deformable sampler ------------------------------------
__global__ __launch_bounds__(256) void k_samp(const void* __restrict__ rb_raw,
                                              const int* __restrict__ flag,
                                              const float* __restrict__ offb,
                                              const float* __restrict__ awb,
                                              const BF* __restrict__ val,
                                              BF* __restrict__ sout)
{
    int fp32 = flag[0];
    int t = threadIdx.x;
    int g = blockIdx.x * 8 + (t >> 5);
    int d = t & 31;
    int l = g & (L_N - 1);
    int h = (g >> 12) & 7;
    int b = g >> 15;
    const float* op = offb + ((long)b * L_N + l) * 64 + h * 8;
    const float* ap = awb + ((long)b * L_N + l) * 32 + h * 4;
    float rx = load_raw(rb_raw, ((long)b * L_N + l) * 2 + 0, fp32);
    float ry = load_raw(rb_raw, ((long)b * L_N + l) * 2 + 1, fp32);
    float lg0 = ap[0], lg1 = ap[1], lg2 = ap[2], lg3 = ap[3];
    float m = fmaxf(fmaxf(lg0, lg1), fmaxf(lg2, lg3));
    float e[4];
    e[0] = __expf(lg0 - m); e[1] = __expf(lg1 - m);
    e[2] = __expf(lg2 - m); e[3] = __expf(lg3 - m);
    float inv = 1.f / (e[0] + e[1] + e[2] + e[3]);
    const BF* vb = val + ((long)(b * 8 + h) * L_N) * 32 + d;
    float o = 0.f;
#pragma unroll
    for (int p = 0; p < 4; p++) {
        float aw = e[p] * inv;
        float gx = rx * 64.f + op[p * 2 + 0] - 0.5f;
        float gy = ry * 64.f + op[p * 2 + 1] - 0.5f;
        float fx = floorf(gx), fy = floorf(gy);
        int x0 = (int)fx, yy0 = (int)fy;
        float wx1 = gx - fx, wy1 = gy - fy;
        float wx0 = 1.f - wx1, wy0 = 1.f - wy1;
        float c00 = 0.f, c10 = 0.f, c01 = 0.f, c11 = 0.f;
        if (x0 >= 0 && x0 < 64 && yy0 >= 0 && yy0 < 64)         c00 = b2f(vb[(long)(yy0 * 64 + x0) * 32]);
        if (x0+1 >= 0 && x0+1 < 64 && yy0 >= 0 && yy0 < 64)     c10 = b2f(vb[(long)(yy0 * 64 + x0 + 1) * 32]);
        if (x0 >= 0 && x0 < 64 && yy0+1 >= 0 && yy0+1 < 64)     c01 = b2f(vb[(long)((yy0 + 1) * 64 + x0) * 32]);
        if (x0+1 >= 0 && x0+1 < 64 && yy0+1 >= 0 && yy0+1 < 64) c11 = b2f(vb[(long)((yy0 + 1) * 64 + x0 + 1) * 32]);
        o += aw * (c00 * wx0 * wy0 + c10 * wx1 * wy0 + c01 * wx0 * wy1 + c11 * wx1 * wy1);
    }
    sout[((long)b * L_N + l) * 256 + h * 32 + d] = f2b(o);
}

extern "C" void kernel_launch(void* const* d_in, const int* in_sizes, int n_in,
                              void* d_out, int out_size, void* d_ws, size_t ws_size,
                              hipStream_t stream)
{
    (void)in_sizes; (void)n_in; (void)out_size; (void)ws_size;
    char* ws = (char*)d_ws;
    size_t woff = 0;
    auto carve = [&](size_t bytes) -> char* {
        char* p = ws + woff;
        woff += (bytes + 255) & ~(size_t)255;
        return p;
    };
    int* flag   = (int*)carve(256);
    BF* cv1_c   = (BF*)carve(262144 * 2);     // [512 oc][512 ic] = wT directly
    BF* cv2_c   = (BF*)carve(655360 * 2);     // [512 oc][1280 ic] = wT directly
    BF* qb      = (BF*)carve(384 * 2);        // vproj_b | off_b | aw_b
    BF* outb_c  = (BF*)carve(256 * 2);
    BF* wTq     = (BF*)carve((size_t)384 * 256 * 2);
    BF* wTo     = (BF*)carve((size_t)256 * 256 * 2);
    BF* wt9_0   = (BF*)carve(589824 * 2);
    BF* wt9_1   = (BF*)carve(589824 * 2);
    BF* wt9_2   = (BF*)carve(589824 * 2);
    BF* wt9_3   = (BF*)carve(589824 * 2);
    BF* cat     = (BF*)carve((size_t)B_N * 1280 * L_N * 2);   // ch-major [a|b|b1|b2|attn]
    // UNION region, 44 MB (disjoint lifetimes):
    //   tmp  U+0      (16MB)  conv chain scratch, dead after m1_cv2
    //   sout U+0      (16MB)  written by samp (after tmp dead), read by outproj
    //   val  U+16MB   (16MB)  qkv -> samp
    //   offb U+32MB   ( 8MB)  qkv -> samp
    //   awb  U+40MB   ( 4MB)  qkv -> samp
    char* U = carve((size_t)46137344);
    BF*    tmp  = (BF*)U;
    BF*    sout = (BF*)U;
    BF*    val  = (BF*)(U + 16777216);
    float* offb = (float*)(U + 33554432);
    float* awb  = (float*)(U + 41943040);

    k_detect<<<1, 256, 0, stream>>>((const ushort_t*)d_in[0], flag);
    // x -> cat ch 512..1023 region (per-batch scatter); read by cv1 only
    k_convert_x<<<1024, 256, 0, stream>>>(d_in[0], cat, flag);
    auto conv = [&](const void* src, BF* dst, int n) {
        int grid = (n + 16383) / 16384; if (grid < 1) grid = 1;
        k_convert<<<grid, 256, 0, stream>>>(src, dst, n, flag);
    };
    conv(d_in[3],  cv1_c,  262144);
    conv(d_in[16], cv2_c,  655360);
    conv(d_in[9],  qb,     256);
    conv(d_in[11], qb + 256, 64);
    conv(d_in[13], qb + 320, 32);
    conv(d_in[15], outb_c, 256);

    // weight transposes (+convert): [ic][oc] -> [oc][ic]
    k_tr_mat<<<dim3(8, 8), 256, 0, stream>>>(d_in[8],  wTq, 256, 256, 256, 0,   flag);
    k_tr_mat<<<dim3(2, 8), 256, 0, stream>>>(d_in[10], wTq, 256, 64,  256, 256, flag);
    k_tr_mat<<<dim3(1, 8), 256, 0, stream>>>(d_in[12], wTq, 256, 32,  256, 320, flag);
    k_zerobf<<<32, 256, 0, stream>>>(wTq + (size_t)352 * 256, 32 * 256);
    k_tr_mat<<<dim3(8, 8), 256, 0, stream>>>(d_in[14], wTo, 256, 256, 256, 0,   flag);
    k_tr_w9<<<256, 256, 0, stream>>>(d_in[4], wt9_0, flag);
    k_tr_w9<<<256, 256, 0, stream>>>(d_in[5], wt9_1, flag);
    k_tr_w9<<<256, 256, 0, stream>>>(d_in[6], wt9_2, flag);
    k_tr_w9<<<256, 256, 0, stream>>>(d_in[7], wt9_3, flag);

    const long CAT = (long)1280 * L_N, C1S = (long)512 * L_N, C0S = (long)256 * L_N;
    // cv1: x (cat ch 512..1023 view, 512ch) -> cat ch 0..511, silu
    k_mconv<1, 64, false><<<dim3(32, 8, 2), 512, 0, stream>>>(
        cat + 2 * C0S, CAT, 0, 512, cv1_c, 512, nullptr, 512, 0,
        cat, nullptr, CAT, nullptr, nullptr, nullptr, nullptr);
    // m0_cv1: b (cat ch 256..511) -> tmp
    k_mconv<9, 32, false><<<dim3(32, 8, 1), 512, 0, stream>>>(
        cat + C0S, CAT, 0, 256, wt9_0, 256, nullptr, 256, 0,
        tmp, nullptr, C0S, nullptr, nullptr, nullptr, nullptr);
    // m0_cv2: tmp -> b1 (cat ch 512..767; x region now dead)
    k_mconv<9, 32, false><<<dim3(32, 8, 1), 512, 0, stream>>>(
        tmp, C0S, 0, 256, wt9_1, 256, nullptr, 256, 0,
        cat + 2 * C0S, nullptr, CAT, nullptr, nullptr, nullptr, nullptr);
    // m1_cv1: b1 -> tmp
    k_mconv<9, 32, false><<<dim3(32, 8, 1), 512, 0, stream>>>(
        cat + 2 * C0S, CAT, 0, 256, wt9_2, 256, nullptr, 256, 0,
        tmp, nullptr, C0S, nullptr, nullptr, nullptr, nullptr);
    // m1_cv2: tmp -> b2 (cat ch 768..1023)
    k_mconv<9, 32, false><<<dim3(32, 8, 1), 512, 0, stream>>>(
        tmp, C0S, 0, 256, wt9_3, 256, nullptr, 256, 0,
        cat + 3 * C0S, nullptr, CAT, nullptr, nullptr, nullptr, nullptr);
    // qkv: b2 -> val / offb / awb  (352 real cols, padded to 384)
    k_mconv<1, 64, false><<<dim3(32, 8, 2), 512, 0, stream>>>(
        cat + 3 * C0S, CAT, 0, 256, wTq, 384, qb, 384, 2,
        nullptr, nullptr, 0, nullptr, val, offb, awb);
    // sampler (tmp dead -> sout reuses U+0)
    k_samp<<<dim3(32768), 256, 0, stream>>>(d_in[1], flag, offb, awb, val, sout);
    // outproj: sout (px-major [px][256]) -> cat ch 1024..1279, +bias, no act
    k_mconv<1, 64, true><<<dim3(32, 8, 1), 512, 0, stream>>>(
        sout, (long)L_N * 256, 256, 256, wTo, 256, outb_c, 256, 3,
        cat + 4 * C0S, nullptr, CAT, nullptr, nullptr, nullptr, nullptr);
    // cv2: cat (1280ch) -> out (512ch), silu, dtype per flag
    k_mconv<1, 64, false><<<dim3(32, 8, 2), 512, 0, stream>>>(
        cat, CAT, 0, 1280, cv2_c, 512, nullptr, 512, 1,
        (BF*)d_out, (float*)d_out, C1S, flag, nullptr, nullptr, nullptr);
}

// Round 7
// 987.033 us; speedup vs baseline: 1.0190x; 1.0190x over previous
//
#include <hip/hip_runtime.h>
#include <hip/hip_bf16.h>

typedef __hip_bfloat16 BF;
typedef unsigned short ushort_t;
typedef __attribute__((ext_vector_type(8))) short short8;
typedef __attribute__((ext_vector_type(4))) short short4v;
typedef __attribute__((ext_vector_type(4))) float f32x4;

#define B_N 8
#define L_N 4096

__device__ __forceinline__ float b2f(BF v){ return __bfloat162float(v); }
__device__ __forceinline__ BF f2b(float v){ return __float2bfloat16(v); }
__device__ __forceinline__ float siluf(float x){ return x / (1.0f + __expf(-x)); }
__device__ __forceinline__ short pks(float v){ BF e = f2b(v); return *(short*)&e; }

// load element idx from raw buffer that is fp32 (flagv=1) or bf16 (0); scrub NaN/Inf
__device__ __forceinline__ float load_raw(const void* src, long idx, int fp32)
{
    if (fp32) {
        float v = ((const float*)src)[idx];
        unsigned u = __float_as_uint(v);
        if ((u & 0x7F800000u) == 0x7F800000u) v = 0.f;
        return v;
    } else {
        ushort_t v = ((const ushort_t*)src)[idx];
        if (((v >> 7) & 0xFF) == 0xFF) v = 0;
        unsigned u = ((unsigned)v) << 16;
        return __uint_as_float(u);
    }
}

// -------- dtype detector: count bf16-NaN/Inf exponent patterns ----------
__global__ __launch_bounds__(256) void k_detect(const ushort_t* __restrict__ x,
                                                int* __restrict__ flag)
{
    __shared__ int cnt[256];
    int t = threadIdx.x;
    int c = 0;
    for (int i = t; i < 65536; i += 256) {
        ushort_t v = x[i];
        if (((v >> 7) & 0xFF) == 0xFF) c++;
    }
    cnt[t] = c;
    __syncthreads();
    for (int s = 128; s > 0; s >>= 1) {
        if (t < s) cnt[t] += cnt[t + s];
        __syncthreads();
    }
    if (t == 0) flag[0] = (cnt[0] > 4) ? 1 : 0;  // 1 => source data is fp32
}

// -------- normalize a float input into clean bf16 -----------------------
__global__ __launch_bounds__(256) void k_convert(const void* __restrict__ src,
                                                 BF* __restrict__ dst, int n,
                                                 const int* __restrict__ flag)
{
    int fp32 = flag[0];
    int i = blockIdx.x * 256 + threadIdx.x;
    int stride = gridDim.x * 256;
    for (; i < n; i += stride) dst[i] = f2b(load_raw(src, i, fp32));
}

// -------- convert x (B,512,L) into cat ch512..1023 region per batch -----
__global__ __launch_bounds__(256) void k_convert_x(const void* __restrict__ src,
                                                   BF* __restrict__ cat,
                                                   const int* __restrict__ flag)
{
    int fp32 = flag[0];
    const long PB = (long)512 * L_N;          // 2,097,152 elems per batch
    const long CAT = (long)1280 * L_N;
    long i = (long)blockIdx.x * 256 + threadIdx.x;
    long stride = (long)gridDim.x * 256;
    for (; i < (long)B_N * PB; i += stride) {
        long b = i / PB, j = i - b * PB;
        cat[b * CAT + PB /*ch512 offset = 512*L_N*/ + j] = f2b(load_raw(src, i, fp32));
    }
}

// ---- zero-fill bf16 region ---------------------------------------------
__global__ __launch_bounds__(256) void k_zerobf(BF* __restrict__ p, int n)
{
    int i = blockIdx.x * 256 + threadIdx.x;
    if (i < n) p[i] = f2b(0.f);
}

// ---- matrix transpose+convert: raw in[r][c] -> out[(c+roff)*opitch + r]
__global__ __launch_bounds__(256) void k_tr_mat(const void* __restrict__ in,
                                                BF* __restrict__ out,
                                                int rows, int cols, int opitch, int roff,
                                                const int* __restrict__ flag)
{
    __shared__ BF tile[32][33];
    int fp32 = flag[0];
    int c0 = blockIdx.x * 32, r0 = blockIdx.y * 32;
    int tx = threadIdx.x & 31, ty = threadIdx.x >> 5;
#pragma unroll
    for (int i = 0; i < 4; i++) {
        int r = r0 + ty + i * 8, c = c0 + tx;
        tile[ty + i * 8][tx] = (r < rows && c < cols) ? f2b(load_raw(in, (long)r * cols + c, fp32))
                                                      : f2b(0.f);
    }
    __syncthreads();
#pragma unroll
    for (int i = 0; i < 4; i++) {
        int c = c0 + ty + i * 8, r = r0 + tx;
        if (c < cols && r < rows) out[(long)(c + roff) * opitch + r] = tile[tx][ty + i * 8];
    }
}

// ---- conv weight transpose+convert: raw w[oc][ic][9] -> wt[tap][oc][ic]
__global__ __launch_bounds__(256) void k_tr_w9(const void* __restrict__ w,
                                               BF* __restrict__ wt,
                                               const int* __restrict__ flag)
{
    int fp32 = flag[0];
    int idx = blockIdx.x * 256 + threadIdx.x;      // 65536 = oc*256+ic
    int oc = idx >> 8, ic = idx & 255;
#pragma unroll
    for (int tap = 0; tap < 9; tap++)
        wt[((long)tap * 256 + oc) * 256 + ic] = f2b(load_raw(w, (long)idx * 9 + tap, fp32));
}

// ============== 3x3 MFMA implicit-GEMM conv (round-5 proven) ============
// 512 thr (8 waves = 2M x 4N), block 128px x 256oc, wave 64x64, KC=32,
// dbuf LDS, single __syncthreads per chunk, weight-tap double-buffering.
template<int TAPS, int KC, bool PXM>
__global__ __launch_bounds__(512, 2) void k_mconv(
    const BF* __restrict__ in, long in_bstride, int ipitch, int cin,
    const BF* __restrict__ wT, int ocp,
    const BF* __restrict__ bias, int coutp, int mode,
    BF* __restrict__ outb, float* __restrict__ outf, long out_bstride,
    const int* __restrict__ flag,
    BF* __restrict__ valp, float* __restrict__ offb, float* __restrict__ awb)
{
    constexpr int NROWS = (TAPS == 9) ? 257 : 128;
    constexpr int PITCH = KC + 8;          // 40 / 72 shorts, b128-aligned rows
    constexpr int NKS   = KC / 32;
    __shared__ short ldsA[2][NROWS * PITCH];

    const int t    = threadIdx.x;
    const int lane = t & 63;
    const int wv   = t >> 6;             // 0..7
    const int ln   = lane & 15;
    const int kg   = lane >> 4;          // 0..3
    const int wr   = wv >> 2;            // 0..1  (M half)
    const int wc   = wv & 3;             // 0..3  (N quarter)
    const int px0  = blockIdx.x * 128;
    const int b    = blockIdx.y;
    const int nbase = blockIdx.z * 256 + wc * 64;
    const bool active = (nbase < coutp);
    const BF* inb = in + (long)b * in_bstride;

    int icp, seg, srow, scol;
    if (PXM)            { srow = t >> 2; scol = (t & 3) * 16; icp = 0; seg = 0; }
    else if (TAPS == 9) { icp = t & 15; seg = t >> 4; srow = 0; scol = 0; }
    else                { icp = t & 31; seg = t >> 5; srow = 0; scol = 0; }
    const int gp0 = (TAPS == 9) ? (px0 - 64 + seg * 8) : (px0 + seg * 8);
    const bool sval = (TAPS != 9) || (gp0 >= 0 && gp0 < L_N);

    if (TAPS == 9) {                      // zero halo row 256 in BOTH buffers
        if (t < 20)            ((unsigned*)&ldsA[0][256 * PITCH])[t] = 0u;
        if (t >= 64 && t < 84) ((unsigned*)&ldsA[1][256 * PITCH])[t - 64] = 0u;
    }

    f32x4 acc[4][4];
#pragma unroll
    for (int mf = 0; mf < 4; mf++)
#pragma unroll
        for (int nf = 0; nf < 4; nf++) {
            f32x4 z = {0.f, 0.f, 0.f, 0.f};
            acc[mf][nf] = z;
        }

    const int nchunks = cin / KC;
    short8 r0, r1;

    auto load_chunk = [&](int c0) {
        if (PXM) {
            const BF* p = inb + (long)(px0 + srow) * ipitch + c0 + scol;
            r0 = *(const short8*)p;
            r1 = *(const short8*)(p + 8);
        } else {
            if (sval) {
                const BF* p0 = inb + (long)(c0 + icp * 2) * L_N + gp0;
                r0 = *(const short8*)p0;
                r1 = *(const short8*)(p0 + L_N);
            }
        }
    };
    auto write_chunk = [&](int buf) {
        if (PXM) {
            *(short8*)&ldsA[buf][srow * PITCH + scol]     = r0;
            *(short8*)&ldsA[buf][srow * PITCH + scol + 8] = r1;
        } else {
#pragma unroll
            for (int k = 0; k < 8; k++) {
                unsigned pk = sval ? ((unsigned)(ushort_t)r0[k] |
                                     ((unsigned)(ushort_t)r1[k] << 16)) : 0u;
                *(unsigned*)&ldsA[buf][(seg * 8 + k) * PITCH + icp * 2] = pk;
            }
        }
    };

    auto wload = [&](int c0, int ks, int tap, int nf) -> short8 {
        int oc = nbase + nf * 16 + ln;
        return *(const short8*)(wT + ((long)(tap * ocp + oc) * cin
                                      + c0 + ks * 32 + kg * 8));
    };

    load_chunk(0);
    write_chunk(0);
    __syncthreads();

    for (int ci = 0; ci < nchunks; ++ci) {
        const int cur = ci & 1;
        const int c0 = ci * KC;
        const bool more = (ci + 1 < nchunks);
        if (more) load_chunk(c0 + KC);          // issue EARLY: hides under MFMA
        __builtin_amdgcn_sched_barrier(0);      // pin prefetch issue before compute
        if (active) {
            short8 bcur[4], bnxt[4];
#pragma unroll
            for (int nf = 0; nf < 4; nf++) bcur[nf] = wload(c0, 0, 0, nf);
#pragma unroll
            for (int ks = 0; ks < NKS; ks++) {
#pragma unroll
                for (int tap = 0; tap < TAPS; ++tap) {
                    const int dy = (TAPS == 9) ? (tap / 3 - 1) : 0;
                    const int dx = (TAPS == 9) ? (tap % 3 - 1) : 0;
                    const bool lastit = (ks == NKS - 1) && (tap == TAPS - 1);
                    if (!lastit) {                  // prefetch next tap's weights
                        const int nks  = (tap == TAPS - 1) ? ks + 1 : ks;
                        const int ntap = (tap == TAPS - 1) ? 0 : tap + 1;
#pragma unroll
                        for (int nf = 0; nf < 4; nf++) bnxt[nf] = wload(c0, nks, ntap, nf);
                    }
                    short8 afr[4];
#pragma unroll
                    for (int mf = 0; mf < 4; mf++) {
                        int ml = wr * 64 + mf * 16 + ln;
                        int row;
                        if (TAPS == 9) {
                            int xs = (ml & 63) + dx;
                            row = (xs >= 0 && xs < 64) ? (ml + dy * 64 + dx + 64) : 256;
                        } else {
                            row = ml;
                        }
                        afr[mf] = *(const short8*)&ldsA[cur][row * PITCH + ks * 32 + kg * 8];
                    }
#pragma unroll
                    for (int mf = 0; mf < 4; mf++)
#pragma unroll
                        for (int nf = 0; nf < 4; nf++)
                            acc[mf][nf] = __builtin_amdgcn_mfma_f32_16x16x32_bf16(
                                afr[mf], bcur[nf], acc[mf][nf], 0, 0, 0);
                    if (!lastit) {
#pragma unroll
                        for (int nf = 0; nf < 4; nf++) bcur[nf] = bnxt[nf];
                    }
                }
            }
        }
        if (more) write_chunk(cur ^ 1);         // LDS write into the OTHER buffer
        __syncthreads();                        // single barrier per chunk
    }
    if (!active) return;

    // ---------------- epilogue (8B vector stores, ch-major out) ---------
    const int wf = (mode == 1 && flag) ? flag[0] : 0;
#pragma unroll
    for (int mf = 0; mf < 4; mf++) {
        int px = px0 + wr * 64 + mf * 16 + kg * 4;
#pragma unroll
        for (int nf = 0; nf < 4; nf++) {
            int oc = nbase + nf * 16 + ln;
            f32x4 a = acc[mf][nf];
            if (mode == 0 || mode == 1) {
                a.x = siluf(a.x); a.y = siluf(a.y); a.z = siluf(a.z); a.w = siluf(a.w);
                if (wf) {
                    float* dst = outf + (long)b * out_bstride + (long)oc * L_N + px;
                    *(f32x4*)dst = a;
                } else {
                    BF* dst = outb + (long)b * out_bstride + (long)oc * L_N + px;
                    short4v sv;
                    sv.x = pks(a.x); sv.y = pks(a.y); sv.z = pks(a.z); sv.w = pks(a.w);
                    *(short4v*)dst = sv;
                }
            } else if (mode == 3) {
                float bs = b2f(bias[oc]);
                BF* dst = outb + (long)b * out_bstride + (long)oc * L_N + px;
                short4v sv;
                sv.x = pks(a.x + bs); sv.y = pks(a.y + bs);
                sv.z = pks(a.z + bs); sv.w = pks(a.w + bs);
                *(short4v*)dst = sv;
            } else {  // mode 2: qkv
                if (oc >= 352) continue;
                float bs = b2f(bias[oc]);
                a.x += bs; a.y += bs; a.z += bs; a.w += bs;
                if (oc < 256) {
                    int h = oc >> 5, d = oc & 31;
                    BF* vp = valp + ((long)(b * 8 + h) * L_N + px) * 32 + d;
                    vp[0] = f2b(a.x); vp[32] = f2b(a.y); vp[64] = f2b(a.z); vp[96] = f2b(a.w);
                } else if (oc < 320) {
                    float* op = offb + ((long)b * L_N + px) * 64 + (oc - 256);
                    op[0] = a.x; op[64] = a.y; op[128] = a.z; op[192] = a.w;
                } else {
                    float* ap = awb + ((long)b * L_N + px) * 32 + (oc - 320);
                    ap[0] = a.x; ap[32] = a.y; ap[64] = a.z; ap[96] = a.w;
                }
            }
        }
    }
}

// ============== 1x1 conv, 256-thr / 4-wave blocks (TLP variant) =========
// Block = 4 waves (2M x 2N), tile 128px x 128oc, wave 64x64, acc[4][4].
// KC=64, dbuf LDS 36.9KB, launch_bounds(256,4) -> 4 blocks/CU = 4
// independent barrier domains (vs 2 at 512thr) for latency hiding.
// z-blocks sharing the A-tile hit L3 (co-resident), so FETCH stays flat.
template<int KC, bool PXM>
__global__ __launch_bounds__(256, 4) void k_mconv1(
    const BF* __restrict__ in, long in_bstride, int ipitch, int cin,
    const BF* __restrict__ wT, int ocp,
    const BF* __restrict__ bias, int coutp, int mode,
    BF* __restrict__ outb, float* __restrict__ outf, long out_bstride,
    const int* __restrict__ flag,
    BF* __restrict__ valp, float* __restrict__ offb, float* __restrict__ awb)
{
    constexpr int PITCH = KC + 8;          // 72 shorts, b128-aligned rows
    constexpr int NKS   = KC / 32;
    __shared__ short ldsA[2][128 * PITCH];

    const int t    = threadIdx.x;
    const int lane = t & 63;
    const int wv   = t >> 6;             // 0..3
    const int ln   = lane & 15;
    const int kg   = lane >> 4;          // 0..3
    const int wr   = wv >> 1;            // 0..1  (M half)
    const int wc   = wv & 1;             // 0..1  (N half)
    const int px0  = blockIdx.x * 128;
    const int b    = blockIdx.y;
    const int nbase = blockIdx.z * 128 + wc * 64;
    const bool active = (nbase < coutp);
    const BF* inb = in + (long)b * in_bstride;

    // staging: 256 thr stage 128px x KC ch per chunk
    //  PXM:      2 thr/row, 64B contiguous each (4x short8)
    //  ch-major: icp=t&31 (32 ch-pairs), seg=t>>5 (8 segs x 16px)
    int icp, seg, srow, scol;
    if (PXM) { srow = t >> 1; scol = (t & 1) * 32; icp = 0; seg = 0; }
    else     { icp = t & 31; seg = t >> 5; srow = 0; scol = 0; }
    const int gp0 = px0 + seg * 16;

    f32x4 acc[4][4];
#pragma unroll
    for (int mf = 0; mf < 4; mf++)
#pragma unroll
        for (int nf = 0; nf < 4; nf++) {
            f32x4 z = {0.f, 0.f, 0.f, 0.f};
            acc[mf][nf] = z;
        }

    const int nchunks = cin / KC;
    short8 q0, q1, q2, q3;

    auto load_chunk = [&](int c0) {
        if (PXM) {
            const BF* p = inb + (long)(px0 + srow) * ipitch + c0 + scol;
            q0 = *(const short8*)p;
            q1 = *(const short8*)(p + 8);
            q2 = *(const short8*)(p + 16);
            q3 = *(const short8*)(p + 24);
        } else {
            const BF* p0 = inb + (long)(c0 + icp * 2) * L_N + gp0;
            q0 = *(const short8*)p0;
            q1 = *(const short8*)(p0 + 8);
            q2 = *(const short8*)(p0 + L_N);
            q3 = *(const short8*)(p0 + L_N + 8);
        }
    };
    auto write_chunk = [&](int buf) {
        if (PXM) {
            *(short8*)&ldsA[buf][srow * PITCH + scol]      = q0;
            *(short8*)&ldsA[buf][srow * PITCH + scol + 8]  = q1;
            *(short8*)&ldsA[buf][srow * PITCH + scol + 16] = q2;
            *(short8*)&ldsA[buf][srow * PITCH + scol + 24] = q3;
        } else {
#pragma unroll
            for (int k = 0; k < 8; k++) {
                unsigned pk = (unsigned)(ushort_t)q0[k] |
                              ((unsigned)(ushort_t)q2[k] << 16);
                *(unsigned*)&ldsA[buf][(seg * 16 + k) * PITCH + icp * 2] = pk;
            }
#pragma unroll
            for (int k = 0; k < 8; k++) {
                unsigned pk = (unsigned)(ushort_t)q1[k] |
                              ((unsigned)(ushort_t)q3[k] << 16);
                *(unsigned*)&ldsA[buf][(seg * 16 + 8 + k) * PITCH + icp * 2] = pk;
            }
        }
    };

    auto wload = [&](int c0, int ks, int nf) -> short8 {
        int oc = nbase + nf * 16 + ln;
        return *(const short8*)(wT + ((long)oc * cin + c0 + ks * 32 + kg * 8));
    };

    load_chunk(0);
    write_chunk(0);
    __syncthreads();

    for (int ci = 0; ci < nchunks; ++ci) {
        const int cur = ci & 1;
        const int c0 = ci * KC;
        const bool more = (ci + 1 < nchunks);
        if (more) load_chunk(c0 + KC);          // issue EARLY: hides under MFMA
        __builtin_amdgcn_sched_barrier(0);      // pin prefetch issue before compute
        if (active) {
            short8 bcur[4], bnxt[4];
#pragma unroll
            for (int nf = 0; nf < 4; nf++) bcur[nf] = wload(c0, 0, nf);
#pragma unroll
            for (int ks = 0; ks < NKS; ks++) {
                const bool lastit = (ks == NKS - 1);
                if (!lastit) {
#pragma unroll
                    for (int nf = 0; nf < 4; nf++) bnxt[nf] = wload(c0, ks + 1, nf);
                }
                short8 afr[4];
#pragma unroll
                for (int mf = 0; mf < 4; mf++) {
                    int row = wr * 64 + mf * 16 + ln;
                    afr[mf] = *(const short8*)&ldsA[cur][row * PITCH + ks * 32 + kg * 8];
                }
#pragma unroll
                for (int mf = 0; mf < 4; mf++)
#pragma unroll
                    for (int nf = 0; nf < 4; nf++)
                        acc[mf][nf] = __builtin_amdgcn_mfma_f32_16x16x32_bf16(
                            afr[mf], bcur[nf], acc[mf][nf], 0, 0, 0);
                if (!lastit) {
#pragma unroll
                    for (int nf = 0; nf < 4; nf++) bcur[nf] = bnxt[nf];
                }
            }
        }
        if (more) write_chunk(cur ^ 1);         // LDS write into the OTHER buffer
        __syncthreads();                        // single barrier per chunk
    }
    if (!active) return;

    // ---------------- epilogue (8B vector stores, ch-major out) ---------
    const int wf = (mode == 1 && flag) ? flag[0] : 0;
#pragma unroll
    for (int mf = 0; mf < 4; mf++) {
        int px = px0 + wr * 64 + mf * 16 + kg * 4;
#pragma unroll
        for (int nf = 0; nf < 4; nf++) {
            int oc = nbase + nf * 16 + ln;
            f32x4 a = acc[mf][nf];
            if (mode == 0 || mode == 1) {
                a.x = siluf(a.x); a.y = siluf(a.y); a.z = siluf(a.z); a.w = siluf(a.w);
                if (wf) {
                    float* dst = outf + (long)b * out_bstride + (long)oc * L_N + px;
                    *(f32x4*)dst = a;
                } else {
                    BF* dst = outb + (long)b * out_bstride + (long)oc * L_N + px;
                    short4v sv;
                    sv.x = pks(a.x); sv.y = pks(a.y); sv.z = pks(a.z); sv.w = pks(a.w);
                    *(short4v*)dst = sv;
                }
            } else if (mode == 3) {
                float bs = b2f(bias[oc]);
                BF* dst = outb + (long)b * out_bstride + (long)oc * L_N + px;
                short4v sv;
                sv.x = pks(a.x + bs); sv.y = pks(a.y + bs);
                sv.z = pks(a.z + bs); sv.w = pks(a.w + bs);
                *(short4v*)dst = sv;
            } else {  // mode 2: qkv
                if (oc >= 352) continue;
                float bs = b2f(bias[oc]);
                a.x += bs; a.y += bs; a.z += bs; a.w += bs;
                if (oc < 256) {
                    int h = oc >> 5, d = oc & 31;
                    BF* vp = valp + ((long)(b * 8 + h) * L_N + px) * 32 + d;
                    vp[0] = f2b(a.x); vp[32] = f2b(a.y); vp[64] = f2b(a.z); vp[96] = f2b(a.w);
                } else if (oc < 320) {
                    float* op = offb + ((long)b * L_N + px) * 64 + (oc - 256);
                    op[0] = a.x; op[64] = a.y; op[128] = a.z; op[192] = a.w;
                } else {
                    float* ap = awb + ((long)b * L_N + px) * 32 + (oc - 320);
                    ap[0] = a.x; ap[32] = a.y; ap[64] = a.z; ap[96] = a.w;
                }
            }
        }
    }
}

// ---------------- deformable sampler ------------------------------------
__global__ __launch_bounds__(256) void k_samp(const void* __restrict__ rb_raw,
                                              const int* __restrict__ flag,
                                              const float* __restrict__ offb,
                                              const float* __restrict__ awb,
                                              const BF* __restrict__ val,
                                              BF* __restrict__ sout)
{
    int fp32 = flag[0];
    int t = threadIdx.x;
    int g = blockIdx.x * 8 + (t >> 5);
    int d = t & 31;
    int l = g & (L_N - 1);
    int h = (g >> 12) & 7;
    int b = g >> 15;
    const float* op = offb + ((long)b * L_N + l) * 64 + h * 8;
    const float* ap = awb + ((long)b * L_N + l) * 32 + h * 4;
    float rx = load_raw(rb_raw, ((long)b * L_N + l) * 2 + 0, fp32);
    float ry = load_raw(rb_raw, ((long)b * L_N + l) * 2 + 1, fp32);
    float lg0 = ap[0], lg1 = ap[1], lg2 = ap[2], lg3 = ap[3];
    float m = fmaxf(fmaxf(lg0, lg1), fmaxf(lg2, lg3));
    float e[4];
    e[0] = __expf(lg0 - m); e[1] = __expf(lg1 - m);
    e[2] = __expf(lg2 - m); e[3] = __expf(lg3 - m);
    float inv = 1.f / (e[0] + e[1] + e[2] + e[3]);
    const BF* vb = val + ((long)(b * 8 + h) * L_N) * 32 + d;
    float o = 0.f;
#pragma unroll
    for (int p = 0; p < 4; p++) {
        float aw = e[p] * inv;
        float gx = rx * 64.f + op[p * 2 + 0] - 0.5f;
        float gy = ry * 64.f + op[p * 2 + 1] - 0.5f;
        float fx = floorf(gx), fy = floorf(gy);
        int x0 = (int)fx, yy0 = (int)fy;
        float wx1 = gx - fx, wy1 = gy - fy;
        float wx0 = 1.f - wx1, wy0 = 1.f - wy1;
        float c00 = 0.f, c10 = 0.f, c01 = 0.f, c11 = 0.f;
        if (x0 >= 0 && x0 < 64 && yy0 >= 0 && yy0 < 64)         c00 = b2f(vb[(long)(yy0 * 64 + x0) * 32]);
        if (x0+1 >= 0 && x0+1 < 64 && yy0 >= 0 && yy0 < 64)     c10 = b2f(vb[(long)(yy0 * 64 + x0 + 1) * 32]);
        if (x0 >= 0 && x0 < 64 && yy0+1 >= 0 && yy0+1 < 64)     c01 = b2f(vb[(long)((yy0 + 1) * 64 + x0) * 32]);
        if (x0+1 >= 0 && x0+1 < 64 && yy0+1 >= 0 && yy0+1 < 64) c11 = b2f(vb[(long)((yy0 + 1) * 64 + x0 + 1) * 32]);
        o += aw * (c00 * wx0 * wy0 + c10 * wx1 * wy0 + c01 * wx0 * wy1 + c11 * wx1 * wy1);
    }
    sout[((long)b * L_N + l) * 256 + h * 32 + d] = f2b(o);
}

extern "C" void kernel_launch(void* const* d_in, const int* in_sizes, int n_in,
                              void* d_out, int out_size, void* d_ws, size_t ws_size,
                              hipStream_t stream)
{
    (void)in_sizes; (void)n_in; (void)out_size; (void)ws_size;
    char* ws = (char*)d_ws;
    size_t woff = 0;
    auto carve = [&](size_t bytes) -> char* {
        char* p = ws + woff;
        woff += (bytes + 255) & ~(size_t)255;
        return p;
    };
    int* flag   = (int*)carve(256);
    BF* cv1_c   = (BF*)carve(262144 * 2);     // [512 oc][512 ic] = wT directly
    BF* cv2_c   = (BF*)carve(655360 * 2);     // [512 oc][1280 ic] = wT directly
    BF* qb      = (BF*)carve(384 * 2);        // vproj_b | off_b | aw_b
    BF* outb_c  = (BF*)carve(256 * 2);
    BF* wTq     = (BF*)carve((size_t)384 * 256 * 2);
    BF* wTo     = (BF*)carve((size_t)256 * 256 * 2);
    BF* wt9_0   = (BF*)carve(589824 * 2);
    BF* wt9_1   = (BF*)carve(589824 * 2);
    BF* wt9_2   = (BF*)carve(589824 * 2);
    BF* wt9_3   = (BF*)carve(589824 * 2);
    BF* cat     = (BF*)carve((size_t)B_N * 1280 * L_N * 2);   // ch-major [a|b|b1|b2|attn]
    // UNION region, 44 MB (disjoint lifetimes):
    //   tmp  U+0      (16MB)  conv chain scratch, dead after m1_cv2
    //   sout U+0      (16MB)  written by samp (after tmp dead), read by outproj
    //   val  U+16MB   (16MB)  qkv -> samp
    //   offb U+32MB   ( 8MB)  qkv -> samp
    //   awb  U+40MB   ( 4MB)  qkv -> samp
    char* U = carve((size_t)46137344);
    BF*    tmp  = (BF*)U;
    BF*    sout = (BF*)U;
    BF*    val  = (BF*)(U + 16777216);
    float* offb = (float*)(U + 33554432);
    float* awb  = (float*)(U + 41943040);

    k_detect<<<1, 256, 0, stream>>>((const ushort_t*)d_in[0], flag);
    // x -> cat ch 512..1023 region (per-batch scatter); read by cv1 only
    k_convert_x<<<1024, 256, 0, stream>>>(d_in[0], cat, flag);
    auto conv = [&](const void* src, BF* dst, int n) {
        int grid = (n + 16383) / 16384; if (grid < 1) grid = 1;
        k_convert<<<grid, 256, 0, stream>>>(src, dst, n, flag);
    };
    conv(d_in[3],  cv1_c,  262144);
    conv(d_in[16], cv2_c,  655360);
    conv(d_in[9],  qb,     256);
    conv(d_in[11], qb + 256, 64);
    conv(d_in[13], qb + 320, 32);
    conv(d_in[15], outb_c, 256);

    // weight transposes (+convert): [ic][oc] -> [oc][ic]
    k_tr_mat<<<dim3(8, 8), 256, 0, stream>>>(d_in[8],  wTq, 256, 256, 256, 0,   flag);
    k_tr_mat<<<dim3(2, 8), 256, 0, stream>>>(d_in[10], wTq, 256, 64,  256, 256, flag);
    k_tr_mat<<<dim3(1, 8), 256, 0, stream>>>(d_in[12], wTq, 256, 32,  256, 320, flag);
    k_zerobf<<<32, 256, 0, stream>>>(wTq + (size_t)352 * 256, 32 * 256);
    k_tr_mat<<<dim3(8, 8), 256, 0, stream>>>(d_in[14], wTo, 256, 256, 256, 0,   flag);
    k_tr_w9<<<256, 256, 0, stream>>>(d_in[4], wt9_0, flag);
    k_tr_w9<<<256, 256, 0, stream>>>(d_in[5], wt9_1, flag);
    k_tr_w9<<<256, 256, 0, stream>>>(d_in[6], wt9_2, flag);
    k_tr_w9<<<256, 256, 0, stream>>>(d_in[7], wt9_3, flag);

    const long CAT = (long)1280 * L_N, C1S = (long)512 * L_N, C0S = (long)256 * L_N;
    // cv1: x (cat ch 512..1023 view, 512ch) -> cat ch 0..511, silu
    k_mconv1<64, false><<<dim3(32, 8, 4), 256, 0, stream>>>(
        cat + 2 * C0S, CAT, 0, 512, cv1_c, 512, nullptr, 512, 0,
        cat, nullptr, CAT, nullptr, nullptr, nullptr, nullptr);
    // m0_cv1: b (cat ch 256..511) -> tmp
    k_mconv<9, 32, false><<<dim3(32, 8, 1), 512, 0, stream>>>(
        cat + C0S, CAT, 0, 256, wt9_0, 256, nullptr, 256, 0,
        tmp, nullptr, C0S, nullptr, nullptr, nullptr, nullptr);
    // m0_cv2: tmp -> b1 (cat ch 512..767; x region now dead)
    k_mconv<9, 32, false><<<dim3(32, 8, 1), 512, 0, stream>>>(
        tmp, C0S, 0, 256, wt9_1, 256, nullptr, 256, 0,
        cat + 2 * C0S, nullptr, CAT, nullptr, nullptr, nullptr, nullptr);
    // m1_cv1: b1 -> tmp
    k_mconv<9, 32, false><<<dim3(32, 8, 1), 512, 0, stream>>>(
        cat + 2 * C0S, CAT, 0, 256, wt9_2, 256, nullptr, 256, 0,
        tmp, nullptr, C0S, nullptr, nullptr, nullptr, nullptr);
    // m1_cv2: tmp -> b2 (cat ch 768..1023)
    k_mconv<9, 32, false><<<dim3(32, 8, 1), 512, 0, stream>>>(
        tmp, C0S, 0, 256, wt9_3, 256, nullptr, 256, 0,
        cat + 3 * C0S, nullptr, CAT, nullptr, nullptr, nullptr, nullptr);
    // qkv: b2 -> val / offb / awb  (352 real cols, padded to 384)
    k_mconv1<64, false><<<dim3(32, 8, 3), 256, 0, stream>>>(
        cat + 3 * C0S, CAT, 0, 256, wTq, 384, qb, 384, 2,
        nullptr, nullptr, 0, nullptr, val, offb, awb);
    // sampler (tmp dead -> sout reuses U+0)
    k_samp<<<dim3(32768), 256, 0, stream>>>(d_in[1], flag, offb, awb, val, sout);
    // outproj: sout (px-major [px][256]) -> cat ch 1024..1279, +bias, no act
    k_mconv1<64, true><<<dim3(32, 8, 2), 256, 0, stream>>>(
        sout, (long)L_N * 256, 256, 256, wTo, 256, outb_c, 256, 3,
        cat + 4 * C0S, nullptr, CAT, nullptr, nullptr, nullptr, nullptr);
    // cv2: cat (1280ch) -> out (512ch), silu, dtype per flag
    k_mconv1<64, false><<<dim3(32, 8, 4), 256, 0, stream>>>(
        cat, CAT, 0, 1280, cv2_c, 512, nullptr, 512, 1,
        (BF*)d_out, (float*)d_out, C1S, flag, nullptr, nullptr, nullptr);
}

// Round 8
// 834.091 us; speedup vs baseline: 1.2058x; 1.1834x over previous
//
#include <hip/hip_runtime.h>
#include <hip/hip_bf16.h>

typedef __hip_bfloat16 BF;
typedef unsigned short ushort_t;
typedef __attribute__((ext_vector_type(8))) short short8;
typedef __attribute__((ext_vector_type(4))) short short4v;
typedef __attribute__((ext_vector_type(4))) float f32x4;

#define B_N 8
#define L_N 4096

__device__ __forceinline__ float b2f(BF v){ return __bfloat162float(v); }
__device__ __forceinline__ BF f2b(float v){ return __float2bfloat16(v); }
__device__ __forceinline__ float siluf(float x){ return x / (1.0f + __expf(-x)); }
__device__ __forceinline__ short pks(float v){ BF e = f2b(v); return *(short*)&e; }

// load element idx from raw buffer that is fp32 (flagv=1) or bf16 (0); scrub NaN/Inf
__device__ __forceinline__ float load_raw(const void* src, long idx, int fp32)
{
    if (fp32) {
        float v = ((const float*)src)[idx];
        unsigned u = __float_as_uint(v);
        if ((u & 0x7F800000u) == 0x7F800000u) v = 0.f;
        return v;
    } else {
        ushort_t v = ((const ushort_t*)src)[idx];
        if (((v >> 7) & 0xFF) == 0xFF) v = 0;
        unsigned u = ((unsigned)v) << 16;
        return __uint_as_float(u);
    }
}

// -------- dtype detector: count bf16-NaN/Inf exponent patterns ----------
__global__ __launch_bounds__(256) void k_detect(const ushort_t* __restrict__ x,
                                                int* __restrict__ flag)
{
    __shared__ int cnt[256];
    int t = threadIdx.x;
    int c = 0;
    for (int i = t; i < 65536; i += 256) {
        ushort_t v = x[i];
        if (((v >> 7) & 0xFF) == 0xFF) c++;
    }
    cnt[t] = c;
    __syncthreads();
    for (int s = 128; s > 0; s >>= 1) {
        if (t < s) cnt[t] += cnt[t + s];
        __syncthreads();
    }
    if (t == 0) flag[0] = (cnt[0] > 4) ? 1 : 0;  // 1 => source data is fp32
}

// -------- normalize a float input into clean bf16 -----------------------
__global__ __launch_bounds__(256) void k_convert(const void* __restrict__ src,
                                                 BF* __restrict__ dst, int n,
                                                 const int* __restrict__ flag)
{
    int fp32 = flag[0];
    int i = blockIdx.x * 256 + threadIdx.x;
    int stride = gridDim.x * 256;
    for (; i < n; i += stride) dst[i] = f2b(load_raw(src, i, fp32));
}

// -------- convert x (B,512,L) into cat ch512..1023 region per batch -----
__global__ __launch_bounds__(256) void k_convert_x(const void* __restrict__ src,
                                                   BF* __restrict__ cat,
                                                   const int* __restrict__ flag)
{
    int fp32 = flag[0];
    const long PB = (long)512 * L_N;          // 2,097,152 elems per batch
    const long CAT = (long)1280 * L_N;
    long i = (long)blockIdx.x * 256 + threadIdx.x;
    long stride = (long)gridDim.x * 256;
    for (; i < (long)B_N * PB; i += stride) {
        long b = i / PB, j = i - b * PB;
        cat[b * CAT + PB /*ch512 offset = 512*L_N*/ + j] = f2b(load_raw(src, i, fp32));
    }
}

// ---- zero-fill bf16 region ---------------------------------------------
__global__ __launch_bounds__(256) void k_zerobf(BF* __restrict__ p, int n)
{
    int i = blockIdx.x * 256 + threadIdx.x;
    if (i < n) p[i] = f2b(0.f);
}

// ---- matrix transpose+convert into FRAGMENT-MAJOR weight layout:
//      raw in[r=ic][c=oc] -> out[((ic>>5)*opitch + oc+roff)*32 + (ic&31)]
//      (wave wload then reads 1KB contiguous: oc -> +64B, kg -> +16B)
__global__ __launch_bounds__(256) void k_tr_mat(const void* __restrict__ in,
                                                BF* __restrict__ out,
                                                int rows, int cols, int opitch, int roff,
                                                const int* __restrict__ flag)
{
    __shared__ BF tile[32][33];
    int fp32 = flag[0];
    int c0 = blockIdx.x * 32, r0 = blockIdx.y * 32;
    int tx = threadIdx.x & 31, ty = threadIdx.x >> 5;
#pragma unroll
    for (int i = 0; i < 4; i++) {
        int r = r0 + ty + i * 8, c = c0 + tx;
        tile[ty + i * 8][tx] = (r < rows && c < cols) ? f2b(load_raw(in, (long)r * cols + c, fp32))
                                                      : f2b(0.f);
    }
    __syncthreads();
#pragma unroll
    for (int i = 0; i < 4; i++) {
        int c = c0 + ty + i * 8, r = r0 + tx;
        if (c < cols && r < rows)
            out[(((long)(r >> 5) * opitch + (c + roff)) << 5) + (r & 31)] = tile[tx][ty + i * 8];
    }
}

// ---- conv weight repack: raw w[oc][ic] -> out[(ic>>5)*ocn + oc][ic&31]
__global__ __launch_bounds__(256) void k_rep_w(const void* __restrict__ in,
                                               BF* __restrict__ out,
                                               int ocn, int cin, int n,
                                               const int* __restrict__ flag)
{
    int fp32 = flag[0];
    int i = blockIdx.x * 256 + threadIdx.x;
    int stride = gridDim.x * 256;
    for (; i < n; i += stride) {
        int oc = i / cin, ic = i - oc * cin;
        out[(((long)(ic >> 5) * ocn + oc) << 5) + (ic & 31)] = f2b(load_raw(in, i, fp32));
    }
}

// ---- conv weight transpose: raw w[oc][ic][9] -> wt[tap][ic>>5][oc][ic&31]
__global__ __launch_bounds__(256) void k_tr_w9(const void* __restrict__ w,
                                               BF* __restrict__ wt,
                                               const int* __restrict__ flag)
{
    int fp32 = flag[0];
    int idx = blockIdx.x * 256 + threadIdx.x;      // 65536 = oc*256+ic
    int oc = idx >> 8, ic = idx & 255;
#pragma unroll
    for (int tap = 0; tap < 9; tap++)
        wt[((((long)tap * 8 + (ic >> 5)) * 256 + oc) << 5) + (ic & 31)]
            = f2b(load_raw(w, (long)idx * 9 + tap, fp32));
}

// ================= universal MFMA implicit-GEMM conv ====================
// Round-5 proven structure: ch-major activations [cin][L], block 128px x
// 256oc, 8 waves 64x64, KC-chunked dbuf LDS, single __syncthreads per
// chunk, weight-tap double-buffering.
// NEW: weights in fragment-major [tap][kb][oc][32] layout -> every wload
// is a fully-coalesced 1KB wave read (8 cache lines vs 64 before).
// modes: 0 = silu->bf16 ch-major | 1 = silu->bf16/fp32 by flag (cv2)
//        2 = qkv epilogue        | 3 = +bias, no act, bf16 ch-major
template<int TAPS, int KC, bool PXM>
__global__ __launch_bounds__(512, 2) void k_mconv(
    const BF* __restrict__ in, long in_bstride, int ipitch, int cin,
    const BF* __restrict__ wT, int ocp,
    const BF* __restrict__ bias, int coutp, int mode,
    BF* __restrict__ outb, float* __restrict__ outf, long out_bstride,
    const int* __restrict__ flag,
    BF* __restrict__ valp, float* __restrict__ offb, float* __restrict__ awb)
{
    constexpr int NROWS = (TAPS == 9) ? 257 : 128;
    constexpr int PITCH = KC + 8;          // 40 / 72 shorts, b128-aligned rows
    constexpr int NKS   = KC / 32;
    __shared__ short ldsA[2][NROWS * PITCH];

    const int t    = threadIdx.x;
    const int lane = t & 63;
    const int wv   = t >> 6;             // 0..7
    const int ln   = lane & 15;
    const int kg   = lane >> 4;          // 0..3
    const int wr   = wv >> 2;            // 0..1  (M half)
    const int wc   = wv & 3;             // 0..3  (N quarter)
    const int px0  = blockIdx.x * 128;
    const int b    = blockIdx.y;
    const int nbase = blockIdx.z * 256 + wc * 64;
    const bool active = (nbase < coutp);
    const BF* inb = in + (long)b * in_bstride;
    const int NKB = cin >> 5;            // 32-ch K-blocks in weight layout

    int icp, seg, srow, scol;
    if (PXM)            { srow = t >> 2; scol = (t & 3) * 16; icp = 0; seg = 0; }
    else if (TAPS == 9) { icp = t & 15; seg = t >> 4; srow = 0; scol = 0; }
    else                { icp = t & 31; seg = t >> 5; srow = 0; scol = 0; }
    const int gp0 = (TAPS == 9) ? (px0 - 64 + seg * 8) : (px0 + seg * 8);
    const bool sval = (TAPS != 9) || (gp0 >= 0 && gp0 < L_N);

    if (TAPS == 9) {                      // zero halo row 256 in BOTH buffers
        if (t < 20)            ((unsigned*)&ldsA[0][256 * PITCH])[t] = 0u;
        if (t >= 64 && t < 84) ((unsigned*)&ldsA[1][256 * PITCH])[t - 64] = 0u;
    }

    f32x4 acc[4][4];
#pragma unroll
    for (int mf = 0; mf < 4; mf++)
#pragma unroll
        for (int nf = 0; nf < 4; nf++) {
            f32x4 z = {0.f, 0.f, 0.f, 0.f};
            acc[mf][nf] = z;
        }

    const int nchunks = cin / KC;
    short8 r0, r1;

    auto load_chunk = [&](int c0) {
        if (PXM) {
            const BF* p = inb + (long)(px0 + srow) * ipitch + c0 + scol;
            r0 = *(const short8*)p;
            r1 = *(const short8*)(p + 8);
        } else {
            if (sval) {
                const BF* p0 = inb + (long)(c0 + icp * 2) * L_N + gp0;
                r0 = *(const short8*)p0;
                r1 = *(const short8*)(p0 + L_N);
            }
        }
    };
    auto write_chunk = [&](int buf) {
        if (PXM) {
            *(short8*)&ldsA[buf][srow * PITCH + scol]     = r0;
            *(short8*)&ldsA[buf][srow * PITCH + scol + 8] = r1;
        } else {
#pragma unroll
            for (int k = 0; k < 8; k++) {
                unsigned pk = sval ? ((unsigned)(ushort_t)r0[k] |
                                     ((unsigned)(ushort_t)r1[k] << 16)) : 0u;
                *(unsigned*)&ldsA[buf][(seg * 8 + k) * PITCH + icp * 2] = pk;
            }
        }
    };

    // fragment-major weight load: wave reads 1KB contiguous
    auto wload = [&](int kb, int tap, int nf) -> short8 {
        int oc = nbase + nf * 16 + ln;
        return *(const short8*)(wT + ((((long)tap * NKB + kb) * ocp + oc) << 5) + kg * 8);
    };

    load_chunk(0);
    write_chunk(0);
    __syncthreads();

    for (int ci = 0; ci < nchunks; ++ci) {
        const int cur = ci & 1;
        const int c0 = ci * KC;
        const int kb0 = ci * NKS;
        const bool more = (ci + 1 < nchunks);
        if (more) load_chunk(c0 + KC);          // issue EARLY: hides under MFMA
        __builtin_amdgcn_sched_barrier(0);      // pin prefetch issue before compute
        if (active) {
            short8 bcur[4], bnxt[4];
#pragma unroll
            for (int nf = 0; nf < 4; nf++) bcur[nf] = wload(kb0, 0, nf);
#pragma unroll
            for (int ks = 0; ks < NKS; ks++) {
#pragma unroll
                for (int tap = 0; tap < TAPS; ++tap) {
                    const int dy = (TAPS == 9) ? (tap / 3 - 1) : 0;
                    const int dx = (TAPS == 9) ? (tap % 3 - 1) : 0;
                    const bool lastit = (ks == NKS - 1) && (tap == TAPS - 1);
                    if (!lastit) {                  // prefetch next tap's weights
                        const int nks  = (tap == TAPS - 1) ? ks + 1 : ks;
                        const int ntap = (tap == TAPS - 1) ? 0 : tap + 1;
#pragma unroll
                        for (int nf = 0; nf < 4; nf++) bnxt[nf] = wload(kb0 + nks, ntap, nf);
                    }
                    short8 afr[4];
#pragma unroll
                    for (int mf = 0; mf < 4; mf++) {
                        int ml = wr * 64 + mf * 16 + ln;
                        int row;
                        if (TAPS == 9) {
                            int xs = (ml & 63) + dx;
                            row = (xs >= 0 && xs < 64) ? (ml + dy * 64 + dx + 64) : 256;
                        } else {
                            row = ml;
                        }
                        afr[mf] = *(const short8*)&ldsA[cur][row * PITCH + ks * 32 + kg * 8];
                    }
#pragma unroll
                    for (int mf = 0; mf < 4; mf++)
#pragma unroll
                        for (int nf = 0; nf < 4; nf++)
                            acc[mf][nf] = __builtin_amdgcn_mfma_f32_16x16x32_bf16(
                                afr[mf], bcur[nf], acc[mf][nf], 0, 0, 0);
                    if (!lastit) {
#pragma unroll
                        for (int nf = 0; nf < 4; nf++) bcur[nf] = bnxt[nf];
                    }
                }
            }
        }
        if (more) write_chunk(cur ^ 1);         // LDS write into the OTHER buffer
        __syncthreads();                        // single barrier per chunk
    }
    if (!active) return;

    // ---------------- epilogue (8B vector stores, ch-major out) ---------
    const int wf = (mode == 1 && flag) ? flag[0] : 0;
#pragma unroll
    for (int mf = 0; mf < 4; mf++) {
        int px = px0 + wr * 64 + mf * 16 + kg * 4;
#pragma unroll
        for (int nf = 0; nf < 4; nf++) {
            int oc = nbase + nf * 16 + ln;
            f32x4 a = acc[mf][nf];
            if (mode == 0 || mode == 1) {
                a.x = siluf(a.x); a.y = siluf(a.y); a.z = siluf(a.z); a.w = siluf(a.w);
                if (wf) {
                    float* dst = outf + (long)b * out_bstride + (long)oc * L_N + px;
                    *(f32x4*)dst = a;
                } else {
                    BF* dst = outb + (long)b * out_bstride + (long)oc * L_N + px;
                    short4v sv;
                    sv.x = pks(a.x); sv.y = pks(a.y); sv.z = pks(a.z); sv.w = pks(a.w);
                    *(short4v*)dst = sv;
                }
            } else if (mode == 3) {
                float bs = b2f(bias[oc]);
                BF* dst = outb + (long)b * out_bstride + (long)oc * L_N + px;
                short4v sv;
                sv.x = pks(a.x + bs); sv.y = pks(a.y + bs);
                sv.z = pks(a.z + bs); sv.w = pks(a.w + bs);
                *(short4v*)dst = sv;
            } else {  // mode 2: qkv
                if (oc >= 352) continue;
                float bs = b2f(bias[oc]);
                a.x += bs; a.y += bs; a.z += bs; a.w += bs;
                if (oc < 256) {
                    int h = oc >> 5, d = oc & 31;
                    BF* vp = valp + ((long)(b * 8 + h) * L_N + px) * 32 + d;
                    vp[0] = f2b(a.x); vp[32] = f2b(a.y); vp[64] = f2b(a.z); vp[96] = f2b(a.w);
                } else if (oc < 320) {
                    float* op = offb + ((long)b * L_N + px) * 64 + (oc - 256);
                    op[0] = a.x; op[64] = a.y; op[128] = a.z; op[192] = a.w;
                } else {
                    float* ap = awb + ((long)b * L_N + px) * 32 + (oc - 320);
                    ap[0] = a.x; ap[32] = a.y; ap[64] = a.z; ap[96] = a.w;
                }
            }
        }
    }
}

// ---------------- deformable sampler ------------------------------------
__global__ __launch_bounds__(256) void k_samp(const void* __restrict__ rb_raw,
                                              const int* __restrict__ flag,
                                              const float* __restrict__ offb,
                                              const float* __restrict__ awb,
                                              const BF* __restrict__ val,
                                              BF* __restrict__ sout)
{
    int fp32 = flag[0];
    int t = threadIdx.x;
    int g = blockIdx.x * 8 + (t >> 5);
    int d = t & 31;
    int l = g & (L_N - 1);
    int h = (g >> 12) & 7;
    int b = g >> 15;
    const float* op = offb + ((long)b * L_N + l) * 64 + h * 8;
    const float* ap = awb + ((long)b * L_N + l) * 32 + h * 4;
    float rx = load_raw(rb_raw, ((long)b * L_N + l) * 2 + 0, fp32);
    float ry = load_raw(rb_raw, ((long)b * L_N + l) * 2 + 1, fp32);
    float lg0 = ap[0], lg1 = ap[1], lg2 = ap[2], lg3 = ap[3];
    float m = fmaxf(fmaxf(lg0, lg1), fmaxf(lg2, lg3));
    float e[4];
    e[0] = __expf(lg0 - m); e[1] = __expf(lg1 - m);
    e[2] = __expf(lg2 - m); e[3] = __expf(lg3 - m);
    float inv = 1.f / (e[0] + e[1] + e[2] + e[3]);
    const BF* vb = val + ((long)(b * 8 + h) * L_N) * 32 + d;
    float o = 0.f;
#pragma unroll
    for (int p = 0; p < 4; p++) {
        float aw = e[p] * inv;
        float gx = rx * 64.f + op[p * 2 + 0] - 0.5f;
        float gy = ry * 64.f + op[p * 2 + 1] - 0.5f;
        float fx = floorf(gx), fy = floorf(gy);
        int x0 = (int)fx, yy0 = (int)fy;
        float wx1 = gx - fx, wy1 = gy - fy;
        float wx0 = 1.f - wx1, wy0 = 1.f - wy1;
        float c00 = 0.f, c10 = 0.f, c01 = 0.f, c11 = 0.f;
        if (x0 >= 0 && x0 < 64 && yy0 >= 0 && yy0 < 64)         c00 = b2f(vb[(long)(yy0 * 64 + x0) * 32]);
        if (x0+1 >= 0 && x0+1 < 64 && yy0 >= 0 && yy0 < 64)     c10 = b2f(vb[(long)(yy0 * 64 + x0 + 1) * 32]);
        if (x0 >= 0 && x0 < 64 && yy0+1 >= 0 && yy0+1 < 64)     c01 = b2f(vb[(long)((yy0 + 1) * 64 + x0) * 32]);
        if (x0+1 >= 0 && x0+1 < 64 && yy0+1 >= 0 && yy0+1 < 64) c11 = b2f(vb[(long)((yy0 + 1) * 64 + x0 + 1) * 32]);
        o += aw * (c00 * wx0 * wy0 + c10 * wx1 * wy0 + c01 * wx0 * wy1 + c11 * wx1 * wy1);
    }
    sout[((long)b * L_N + l) * 256 + h * 32 + d] = f2b(o);
}

extern "C" void kernel_launch(void* const* d_in, const int* in_sizes, int n_in,
                              void* d_out, int out_size, void* d_ws, size_t ws_size,
                              hipStream_t stream)
{
    (void)in_sizes; (void)n_in; (void)out_size; (void)ws_size;
    char* ws = (char*)d_ws;
    size_t woff = 0;
    auto carve = [&](size_t bytes) -> char* {
        char* p = ws + woff;
        woff += (bytes + 255) & ~(size_t)255;
        return p;
    };
    int* flag   = (int*)carve(256);
    BF* cv1_c   = (BF*)carve(262144 * 2);     // [16 kb][512 oc][32]
    BF* cv2_c   = (BF*)carve(655360 * 2);     // [40 kb][512 oc][32]
    BF* qb      = (BF*)carve(384 * 2);        // vproj_b | off_b | aw_b
    BF* outb_c  = (BF*)carve(256 * 2);
    BF* wTq     = (BF*)carve((size_t)384 * 256 * 2);   // [8 kb][384 oc][32]
    BF* wTo     = (BF*)carve((size_t)256 * 256 * 2);   // [8 kb][256 oc][32]
    BF* wt9_0   = (BF*)carve(589824 * 2);     // [9 tap][8 kb][256 oc][32]
    BF* wt9_1   = (BF*)carve(589824 * 2);
    BF* wt9_2   = (BF*)carve(589824 * 2);
    BF* wt9_3   = (BF*)carve(589824 * 2);
    BF* cat     = (BF*)carve((size_t)B_N * 1280 * L_N * 2);   // ch-major [a|b|b1|b2|attn]
    // UNION region, 44 MB (disjoint lifetimes):
    //   tmp  U+0      (16MB)  conv chain scratch, dead after m1_cv2
    //   sout U+0      (16MB)  written by samp (after tmp dead), read by outproj
    //   val  U+16MB   (16MB)  qkv -> samp
    //   offb U+32MB   ( 8MB)  qkv -> samp
    //   awb  U+40MB   ( 4MB)  qkv -> samp
    char* U = carve((size_t)46137344);
    BF*    tmp  = (BF*)U;
    BF*    sout = (BF*)U;
    BF*    val  = (BF*)(U + 16777216);
    float* offb = (float*)(U + 33554432);
    float* awb  = (float*)(U + 41943040);

    k_detect<<<1, 256, 0, stream>>>((const ushort_t*)d_in[0], flag);
    // x -> cat ch 512..1023 region (per-batch scatter); read by cv1 only
    k_convert_x<<<1024, 256, 0, stream>>>(d_in[0], cat, flag);
    auto conv = [&](const void* src, BF* dst, int n) {
        int grid = (n + 16383) / 16384; if (grid < 1) grid = 1;
        k_convert<<<grid, 256, 0, stream>>>(src, dst, n, flag);
    };
    conv(d_in[9],  qb,     256);
    conv(d_in[11], qb + 256, 64);
    conv(d_in[13], qb + 320, 32);
    conv(d_in[15], outb_c, 256);

    // conv weights: raw [oc][ic] -> fragment-major [kb][oc][32]
    k_rep_w<<<16, 256, 0, stream>>>(d_in[3],  cv1_c, 512, 512,  262144, flag);
    k_rep_w<<<40, 256, 0, stream>>>(d_in[16], cv2_c, 512, 1280, 655360, flag);

    // linear weights: raw [ic][oc] -> fragment-major [kb][oc+roff][32]
    k_zerobf<<<384, 256, 0, stream>>>(wTq, 98304);     // zero all (pad oc 352..383)
    k_tr_mat<<<dim3(8, 8), 256, 0, stream>>>(d_in[8],  wTq, 256, 256, 384, 0,   flag);
    k_tr_mat<<<dim3(2, 8), 256, 0, stream>>>(d_in[10], wTq, 256, 64,  384, 256, flag);
    k_tr_mat<<<dim3(1, 8), 256, 0, stream>>>(d_in[12], wTq, 256, 32,  384, 320, flag);
    k_tr_mat<<<dim3(8, 8), 256, 0, stream>>>(d_in[14], wTo, 256, 256, 256, 0,   flag);
    k_tr_w9<<<256, 256, 0, stream>>>(d_in[4], wt9_0, flag);
    k_tr_w9<<<256, 256, 0, stream>>>(d_in[5], wt9_1, flag);
    k_tr_w9<<<256, 256, 0, stream>>>(d_in[6], wt9_2, flag);
    k_tr_w9<<<256, 256, 0, stream>>>(d_in[7], wt9_3, flag);

    const long CAT = (long)1280 * L_N, C1S = (long)512 * L_N, C0S = (long)256 * L_N;
    // cv1: x (cat ch 512..1023 view, 512ch) -> cat ch 0..511, silu
    k_mconv<1, 64, false><<<dim3(32, 8, 2), 512, 0, stream>>>(
        cat + 2 * C0S, CAT, 0, 512, cv1_c, 512, nullptr, 512, 0,
        cat, nullptr, CAT, nullptr, nullptr, nullptr, nullptr);
    // m0_cv1: b (cat ch 256..511) -> tmp
    k_mconv<9, 32, false><<<dim3(32, 8, 1), 512, 0, stream>>>(
        cat + C0S, CAT, 0, 256, wt9_0, 256, nullptr, 256, 0,
        tmp, nullptr, C0S, nullptr, nullptr, nullptr, nullptr);
    // m0_cv2: tmp -> b1 (cat ch 512..767; x region now dead)
    k_mconv<9, 32, false><<<dim3(32, 8, 1), 512, 0, stream>>>(
        tmp, C0S, 0, 256, wt9_1, 256, nullptr, 256, 0,
        cat + 2 * C0S, nullptr, CAT, nullptr, nullptr, nullptr, nullptr);
    // m1_cv1: b1 -> tmp
    k_mconv<9, 32, false><<<dim3(32, 8, 1), 512, 0, stream>>>(
        cat + 2 * C0S, CAT, 0, 256, wt9_2, 256, nullptr, 256, 0,
        tmp, nullptr, C0S, nullptr, nullptr, nullptr, nullptr);
    // m1_cv2: tmp -> b2 (cat ch 768..1023)
    k_mconv<9, 32, false><<<dim3(32, 8, 1), 512, 0, stream>>>(
        tmp, C0S, 0, 256, wt9_3, 256, nullptr, 256, 0,
        cat + 3 * C0S, nullptr, CAT, nullptr, nullptr, nullptr, nullptr);
    // qkv: b2 -> val / offb / awb  (352 real cols, padded to 384)
    k_mconv<1, 64, false><<<dim3(32, 8, 2), 512, 0, stream>>>(
        cat + 3 * C0S, CAT, 0, 256, wTq, 384, qb, 384, 2,
        nullptr, nullptr, 0, nullptr, val, offb, awb);
    // sampler (tmp dead -> sout reuses U+0)
    k_samp<<<dim3(32768), 256, 0, stream>>>(d_in[1], flag, offb, awb, val, sout);
    // outproj: sout (px-major [px][256]) -> cat ch 1024..1279, +bias, no act
    k_mconv<1, 64, true><<<dim3(32, 8, 1), 512, 0, stream>>>(
        sout, (long)L_N * 256, 256, 256, wTo, 256, outb_c, 256, 3,
        cat + 4 * C0S, nullptr, CAT, nullptr, nullptr, nullptr, nullptr);
    // cv2: cat (1280ch) -> out (512ch), silu, dtype per flag
    k_mconv<1, 64, false><<<dim3(32, 8, 2), 512, 0, stream>>>(
        cat, CAT, 0, 1280, cv2_c, 512, nullptr, 512, 1,
        (BF*)d_out, (float*)d_out, C1S, flag, nullptr, nullptr, nullptr);
}

// Round 10
// 765.779 us; speedup vs baseline: 1.3134x; 1.0892x over previous
//
#include <hip/hip_runtime.h>
#include <hip/hip_bf16.h>

typedef __hip_bfloat16 BF;
typedef unsigned short ushort_t;
typedef __attribute__((ext_vector_type(8))) short short8;
typedef __attribute__((ext_vector_type(4))) short short4v;
typedef __attribute__((ext_vector_type(4))) float f32x4;

#define B_N 8
#define L_N 4096

__device__ __forceinline__ float b2f(BF v){ return __bfloat162float(v); }
__device__ __forceinline__ BF f2b(float v){ return __float2bfloat16(v); }
__device__ __forceinline__ float siluf(float x){ return x / (1.0f + __expf(-x)); }
__device__ __forceinline__ float s2f(short s){ return __uint_as_float(((unsigned)(ushort_t)s) << 16); }
__device__ __forceinline__ short pks(float v){ BF e = f2b(v); return *(short*)&e; }

// load element idx from raw buffer that is fp32 (flagv=1) or bf16 (0); scrub NaN/Inf
__device__ __forceinline__ float load_raw(const void* src, long idx, int fp32)
{
    if (fp32) {
        float v = ((const float*)src)[idx];
        unsigned u = __float_as_uint(v);
        if ((u & 0x7F800000u) == 0x7F800000u) v = 0.f;
        return v;
    } else {
        ushort_t v = ((const ushort_t*)src)[idx];
        if (((v >> 7) & 0xFF) == 0xFF) v = 0;
        unsigned u = ((unsigned)v) << 16;
        return __uint_as_float(u);
    }
}

// -------- dtype detector: count bf16-NaN/Inf exponent patterns ----------
__global__ __launch_bounds__(256) void k_detect(const ushort_t* __restrict__ x,
                                                int* __restrict__ flag)
{
    __shared__ int cnt[256];
    int t = threadIdx.x;
    int c = 0;
    for (int i = t; i < 65536; i += 256) {
        ushort_t v = x[i];
        if (((v >> 7) & 0xFF) == 0xFF) c++;
    }
    cnt[t] = c;
    __syncthreads();
    for (int s = 128; s > 0; s >>= 1) {
        if (t < s) cnt[t] += cnt[t + s];
        __syncthreads();
    }
    if (t == 0) flag[0] = (cnt[0] > 4) ? 1 : 0;  // 1 => source data is fp32
}

// -------- normalize a float input into clean bf16 -----------------------
__global__ __launch_bounds__(256) void k_convert(const void* __restrict__ src,
                                                 BF* __restrict__ dst, int n,
                                                 const int* __restrict__ flag)
{
    int fp32 = flag[0];
    int i = blockIdx.x * 256 + threadIdx.x;
    int stride = gridDim.x * 256;
    for (; i < n; i += stride) dst[i] = f2b(load_raw(src, i, fp32));
}

// -------- convert x (B,512,L) into cat ch512..1023 region per batch -----
__global__ __launch_bounds__(256) void k_convert_x(const void* __restrict__ src,
                                                   BF* __restrict__ cat,
                                                   const int* __restrict__ flag)
{
    int fp32 = flag[0];
    const long PB = (long)512 * L_N;          // 2,097,152 elems per batch
    const long CAT = (long)1280 * L_N;
    long i = (long)blockIdx.x * 256 + threadIdx.x;
    long stride = (long)gridDim.x * 256;
    for (; i < (long)B_N * PB; i += stride) {
        long b = i / PB, j = i - b * PB;
        cat[b * CAT + PB /*ch512 offset = 512*L_N*/ + j] = f2b(load_raw(src, i, fp32));
    }
}

// ---- zero-fill bf16 region ---------------------------------------------
__global__ __launch_bounds__(256) void k_zerobf(BF* __restrict__ p, int n)
{
    int i = blockIdx.x * 256 + threadIdx.x;
    if (i < n) p[i] = f2b(0.f);
}

// ---- matrix transpose+convert into FRAGMENT-MAJOR weight layout:
//      raw in[r=ic][c=oc] -> out[((ic>>5)*opitch + oc+roff)*32 + (ic&31)]
//      (wave wload then reads 1KB contiguous: oc -> +64B, kg -> +16B)
__global__ __launch_bounds__(256) void k_tr_mat(const void* __restrict__ in,
                                                BF* __restrict__ out,
                                                int rows, int cols, int opitch, int roff,
                                                const int* __restrict__ flag)
{
    __shared__ BF tile[32][33];
    int fp32 = flag[0];
    int c0 = blockIdx.x * 32, r0 = blockIdx.y * 32;
    int tx = threadIdx.x & 31, ty = threadIdx.x >> 5;
#pragma unroll
    for (int i = 0; i < 4; i++) {
        int r = r0 + ty + i * 8, c = c0 + tx;
        tile[ty + i * 8][tx] = (r < rows && c < cols) ? f2b(load_raw(in, (long)r * cols + c, fp32))
                                                      : f2b(0.f);
    }
    __syncthreads();
#pragma unroll
    for (int i = 0; i < 4; i++) {
        int c = c0 + ty + i * 8, r = r0 + tx;
        if (c < cols && r < rows)
            out[(((long)(r >> 5) * opitch + (c + roff)) << 5) + (r & 31)] = tile[tx][ty + i * 8];
    }
}

// ---- conv weight repack: raw w[oc][ic] -> out[(ic>>5)*ocn + oc][ic&31]
__global__ __launch_bounds__(256) void k_rep_w(const void* __restrict__ in,
                                               BF* __restrict__ out,
                                               int ocn, int cin, int n,
                                               const int* __restrict__ flag)
{
    int fp32 = flag[0];
    int i = blockIdx.x * 256 + threadIdx.x;
    int stride = gridDim.x * 256;
    for (; i < n; i += stride) {
        int oc = i / cin, ic = i - oc * cin;
        out[(((long)(ic >> 5) * ocn + oc) << 5) + (ic & 31)] = f2b(load_raw(in, i, fp32));
    }
}

// ---- conv weight transpose: raw w[oc][ic][9] -> wt[tap][ic>>5][oc][ic&31]
__global__ __launch_bounds__(256) void k_tr_w9(const void* __restrict__ w,
                                               BF* __restrict__ wt,
                                               const int* __restrict__ flag)
{
    int fp32 = flag[0];
    int idx = blockIdx.x * 256 + threadIdx.x;      // 65536 = oc*256+ic
    int oc = idx >> 8, ic = idx & 255;
#pragma unroll
    for (int tap = 0; tap < 9; tap++)
        wt[((((long)tap * 8 + (ic >> 5)) * 256 + oc) << 5) + (ic & 31)]
            = f2b(load_raw(w, (long)idx * 9 + tap, fp32));
}

// ================= universal MFMA implicit-GEMM conv ====================
// Round-8 proven structure: ch-major activations [cin][L], block 128px x
// 256oc, 8 waves 64x64, KC-chunked dbuf LDS, single __syncthreads per
// chunk, weight-tap double-buffering, fragment-major weights
// [tap][kb][oc][32] -> every wload is a fully-coalesced 1KB wave read.
// modes: 0 = silu->bf16 ch-major | 1 = silu->bf16/fp32 by flag (cv2)
//        2 = qkv epilogue        | 3 = +bias, no act, bf16 ch-major
template<int TAPS, int KC, bool PXM>
__global__ __launch_bounds__(512, 2) void k_mconv(
    const BF* __restrict__ in, long in_bstride, int ipitch, int cin,
    const BF* __restrict__ wT, int ocp,
    const BF* __restrict__ bias, int coutp, int mode,
    BF* __restrict__ outb, float* __restrict__ outf, long out_bstride,
    const int* __restrict__ flag,
    BF* __restrict__ valp, float* __restrict__ offb, float* __restrict__ awb)
{
    constexpr int NROWS = (TAPS == 9) ? 257 : 128;
    constexpr int PITCH = KC + 8;          // 40 / 72 shorts, b128-aligned rows
    constexpr int NKS   = KC / 32;
    __shared__ short ldsA[2][NROWS * PITCH];

    const int t    = threadIdx.x;
    const int lane = t & 63;
    const int wv   = t >> 6;             // 0..7
    const int ln   = lane & 15;
    const int kg   = lane >> 4;          // 0..3
    const int wr   = wv >> 2;            // 0..1  (M half)
    const int wc   = wv & 3;             // 0..3  (N quarter)
    const int px0  = blockIdx.x * 128;
    const int b    = blockIdx.y;
    const int nbase = blockIdx.z * 256 + wc * 64;
    const bool active = (nbase < coutp);
    const BF* inb = in + (long)b * in_bstride;
    const int NKB = cin >> 5;            // 32-ch K-blocks in weight layout

    int icp, seg, srow, scol;
    if (PXM)            { srow = t >> 2; scol = (t & 3) * 16; icp = 0; seg = 0; }
    else if (TAPS == 9) { icp = t & 15; seg = t >> 4; srow = 0; scol = 0; }
    else                { icp = t & 31; seg = t >> 5; srow = 0; scol = 0; }
    const int gp0 = (TAPS == 9) ? (px0 - 64 + seg * 8) : (px0 + seg * 8);
    const bool sval = (TAPS != 9) || (gp0 >= 0 && gp0 < L_N);

    if (TAPS == 9) {                      // zero halo row 256 in BOTH buffers
        if (t < 20)            ((unsigned*)&ldsA[0][256 * PITCH])[t] = 0u;
        if (t >= 64 && t < 84) ((unsigned*)&ldsA[1][256 * PITCH])[t - 64] = 0u;
    }

    f32x4 acc[4][4];
#pragma unroll
    for (int mf = 0; mf < 4; mf++)
#pragma unroll
        for (int nf = 0; nf < 4; nf++) {
            f32x4 z = {0.f, 0.f, 0.f, 0.f};
            acc[mf][nf] = z;
        }

    const int nchunks = cin / KC;
    short8 r0, r1;

    auto load_chunk = [&](int c0) {
        if (PXM) {
            const BF* p = inb + (long)(px0 + srow) * ipitch + c0 + scol;
            r0 = *(const short8*)p;
            r1 = *(const short8*)(p + 8);
        } else {
            if (sval) {
                const BF* p0 = inb + (long)(c0 + icp * 2) * L_N + gp0;
                r0 = *(const short8*)p0;
                r1 = *(const short8*)(p0 + L_N);
            }
        }
    };
    auto write_chunk = [&](int buf) {
        if (PXM) {
            *(short8*)&ldsA[buf][srow * PITCH + scol]     = r0;
            *(short8*)&ldsA[buf][srow * PITCH + scol + 8] = r1;
        } else {
#pragma unroll
            for (int k = 0; k < 8; k++) {
                unsigned pk = sval ? ((unsigned)(ushort_t)r0[k] |
                                     ((unsigned)(ushort_t)r1[k] << 16)) : 0u;
                *(unsigned*)&ldsA[buf][(seg * 8 + k) * PITCH + icp * 2] = pk;
            }
        }
    };

    // fragment-major weight load: wave reads 1KB contiguous
    auto wload = [&](int kb, int tap, int nf) -> short8 {
        int oc = nbase + nf * 16 + ln;
        return *(const short8*)(wT + ((((long)tap * NKB + kb) * ocp + oc) << 5) + kg * 8);
    };

    load_chunk(0);
    write_chunk(0);
    __syncthreads();

    for (int ci = 0; ci < nchunks; ++ci) {
        const int cur = ci & 1;
        const int c0 = ci * KC;
        const int kb0 = ci * NKS;
        const bool more = (ci + 1 < nchunks);
        if (more) load_chunk(c0 + KC);          // issue EARLY: hides under MFMA
        __builtin_amdgcn_sched_barrier(0);      // pin prefetch issue before compute
        if (active) {
            short8 bcur[4], bnxt[4];
#pragma unroll
            for (int nf = 0; nf < 4; nf++) bcur[nf] = wload(kb0, 0, nf);
#pragma unroll
            for (int ks = 0; ks < NKS; ks++) {
#pragma unroll
                for (int tap = 0; tap < TAPS; ++tap) {
                    const int dy = (TAPS == 9) ? (tap / 3 - 1) : 0;
                    const int dx = (TAPS == 9) ? (tap % 3 - 1) : 0;
                    const bool lastit = (ks == NKS - 1) && (tap == TAPS - 1);
                    if (!lastit) {                  // prefetch next tap's weights
                        const int nks  = (tap == TAPS - 1) ? ks + 1 : ks;
                        const int ntap = (tap == TAPS - 1) ? 0 : tap + 1;
#pragma unroll
                        for (int nf = 0; nf < 4; nf++) bnxt[nf] = wload(kb0 + nks, ntap, nf);
                    }
                    short8 afr[4];
#pragma unroll
                    for (int mf = 0; mf < 4; mf++) {
                        int ml = wr * 64 + mf * 16 + ln;
                        int row;
                        if (TAPS == 9) {
                            int xs = (ml & 63) + dx;
                            row = (xs >= 0 && xs < 64) ? (ml + dy * 64 + dx + 64) : 256;
                        } else {
                            row = ml;
                        }
                        afr[mf] = *(const short8*)&ldsA[cur][row * PITCH + ks * 32 + kg * 8];
                    }
#pragma unroll
                    for (int mf = 0; mf < 4; mf++)
#pragma unroll
                        for (int nf = 0; nf < 4; nf++)
                            acc[mf][nf] = __builtin_amdgcn_mfma_f32_16x16x32_bf16(
                                afr[mf], bcur[nf], acc[mf][nf], 0, 0, 0);
                    if (!lastit) {
#pragma unroll
                        for (int nf = 0; nf < 4; nf++) bcur[nf] = bnxt[nf];
                    }
                }
            }
        }
        if (more) write_chunk(cur ^ 1);         // LDS write into the OTHER buffer
        __syncthreads();                        // single barrier per chunk
    }
    if (!active) return;

    // ---------------- epilogue (8B vector stores, ch-major out) ---------
    const int wf = (mode == 1 && flag) ? flag[0] : 0;
#pragma unroll
    for (int mf = 0; mf < 4; mf++) {
        int px = px0 + wr * 64 + mf * 16 + kg * 4;
#pragma unroll
        for (int nf = 0; nf < 4; nf++) {
            int oc = nbase + nf * 16 + ln;
            f32x4 a = acc[mf][nf];
            if (mode == 0 || mode == 1) {
                a.x = siluf(a.x); a.y = siluf(a.y); a.z = siluf(a.z); a.w = siluf(a.w);
                if (wf) {
                    float* dst = outf + (long)b * out_bstride + (long)oc * L_N + px;
                    *(f32x4*)dst = a;
                } else {
                    BF* dst = outb + (long)b * out_bstride + (long)oc * L_N + px;
                    short4v sv;
                    sv.x = pks(a.x); sv.y = pks(a.y); sv.z = pks(a.z); sv.w = pks(a.w);
                    *(short4v*)dst = sv;
                }
            } else if (mode == 3) {
                float bs = b2f(bias[oc]);
                BF* dst = outb + (long)b * out_bstride + (long)oc * L_N + px;
                short4v sv;
                sv.x = pks(a.x + bs); sv.y = pks(a.y + bs);
                sv.z = pks(a.z + bs); sv.w = pks(a.w + bs);
                *(short4v*)dst = sv;
            } else {  // mode 2: qkv
                if (oc >= 352) continue;
                float bs = b2f(bias[oc]);
                a.x += bs; a.y += bs; a.z += bs; a.w += bs;
                if (oc < 256) {
                    int h = oc >> 5, d = oc & 31;
                    BF* vp = valp + ((long)(b * 8 + h) * L_N + px) * 32 + d;
                    vp[0] = f2b(a.x); vp[32] = f2b(a.y); vp[64] = f2b(a.z); vp[96] = f2b(a.w);
                } else if (oc < 320) {
                    float* op = offb + ((long)b * L_N + px) * 64 + (oc - 256);
                    op[0] = a.x; op[64] = a.y; op[128] = a.z; op[192] = a.w;
                } else {
                    float* ap = awb + ((long)b * L_N + px) * 32 + (oc - 320);
                    ap[0] = a.x; ap[32] = a.y; ap[64] = a.z; ap[96] = a.w;
                }
            }
        }
    }
}

// ---- softmax over the 4 attn-weight logits per (b,l,h), in place -------
// awb layout: [(b*L+l)*8 + h] float4s, contiguous -> trivially coalesced.
__global__ __launch_bounds__(256) void k_softaw(float* __restrict__ awb, int n)
{
    int i = blockIdx.x * 256 + threadIdx.x;
    if (i >= n) return;
    f32x4 a = *(f32x4*)(awb + (long)i * 4);
    float m = fmaxf(fmaxf(a.x, a.y), fmaxf(a.z, a.w));
    float e0 = __expf(a.x - m), e1 = __expf(a.y - m);
    float e2 = __expf(a.z - m), e3 = __expf(a.w - m);
    float inv = 1.f / (e0 + e1 + e2 + e3);
    f32x4 r; r.x = e0 * inv; r.y = e1 * inv; r.z = e2 * inv; r.w = e3 * inv;
    *(f32x4*)(awb + (long)i * 4) = r;
}

// ---------------- deformable sampler ------------------------------------
// 8 lanes per (b,l,h) group; each lane handles 4 consecutive d via 8B
// short4v gathers.  Softmax pre-applied by k_softaw (awb holds weights).
__global__ __launch_bounds__(256) void k_samp(const void* __restrict__ rb_raw,
                                              const int* __restrict__ flag,
                                              const float* __restrict__ offb,
                                              const float* __restrict__ awb,
                                              const BF* __restrict__ val,
                                              BF* __restrict__ sout)
{
    int fp32 = flag[0];
    int t = threadIdx.x;
    int g = blockIdx.x * 32 + (t >> 3);   // group = (b,l,h)
    int dq = t & 7;                        // handles d = dq*4 .. dq*4+3
    int l = g & (L_N - 1);
    int h = (g >> 12) & 7;
    int b = g >> 15;
    const float* op = offb + ((long)b * L_N + l) * 64 + h * 8;
    const float* ap = awb + ((long)b * L_N + l) * 32 + h * 4;   // normalized
    float rx = load_raw(rb_raw, ((long)b * L_N + l) * 2 + 0, fp32) * 64.f - 0.5f;
    float ry = load_raw(rb_raw, ((long)b * L_N + l) * 2 + 1, fp32) * 64.f - 0.5f;
    const BF* vb = val + ((long)(b * 8 + h) * L_N) * 32 + dq * 4;
    float o0 = 0.f, o1 = 0.f, o2 = 0.f, o3 = 0.f;
    short4v z4 = {0, 0, 0, 0};
#pragma unroll
    for (int p = 0; p < 4; p++) {
        float aw = ap[p];
        float gx = rx + op[p * 2 + 0];
        float gy = ry + op[p * 2 + 1];
        float fx = floorf(gx), fy = floorf(gy);
        int x0 = (int)fx, y0 = (int)fy;
        float wx1 = gx - fx, wy1 = gy - fy;
        float wx0 = 1.f - wx1, wy0 = 1.f - wy1;
        float w00 = aw * wx0 * wy0, w10 = aw * wx1 * wy0;
        float w01 = aw * wx0 * wy1, w11 = aw * wx1 * wy1;
        bool vx0 = ((unsigned)x0 < 64u), vx1 = ((unsigned)(x0 + 1) < 64u);
        bool vy0 = ((unsigned)y0 < 64u), vy1 = ((unsigned)(y0 + 1) < 64u);
        const BF* pr0 = vb + (long)(y0 * 64 + x0) * 32;
        short4v v00 = (vx0 && vy0) ? *(const short4v*)(pr0)            : z4;
        short4v v10 = (vx1 && vy0) ? *(const short4v*)(pr0 + 32)       : z4;
        short4v v01 = (vx0 && vy1) ? *(const short4v*)(pr0 + 64 * 32)  : z4;
        short4v v11 = (vx1 && vy1) ? *(const short4v*)(pr0 + 65 * 32)  : z4;
        o0 += s2f(v00.x) * w00 + s2f(v10.x) * w10 + s2f(v01.x) * w01 + s2f(v11.x) * w11;
        o1 += s2f(v00.y) * w00 + s2f(v10.y) * w10 + s2f(v01.y) * w01 + s2f(v11.y) * w11;
        o2 += s2f(v00.z) * w00 + s2f(v10.z) * w10 + s2f(v01.z) * w01 + s2f(v11.z) * w11;
        o3 += s2f(v00.w) * w00 + s2f(v10.w) * w10 + s2f(v01.w) * w01 + s2f(v11.w) * w11;
    }
    short4v sv;
    sv.x = pks(o0); sv.y = pks(o1); sv.z = pks(o2); sv.w = pks(o3);
    *(short4v*)(sout + ((long)b * L_N + l) * 256 + h * 32 + dq * 4) = sv;
}

extern "C" void kernel_launch(void* const* d_in, const int* in_sizes, int n_in,
                              void* d_out, int out_size, void* d_ws, size_t ws_size,
                              hipStream_t stream)
{
    (void)in_sizes; (void)n_in; (void)out_size; (void)ws_size;
    char* ws = (char*)d_ws;
    size_t woff = 0;
    auto carve = [&](size_t bytes) -> char* {
        char* p = ws + woff;
        woff += (bytes + 255) & ~(size_t)255;
        return p;
    };
    int* flag   = (int*)carve(256);
    BF* cv1_c   = (BF*)carve(262144 * 2);     // [16 kb][512 oc][32]
    BF* cv2_c   = (BF*)carve(655360 * 2);     // [40 kb][512 oc][32]
    BF* qb      = (BF*)carve(384 * 2);        // vproj_b | off_b | aw_b
    BF* outb_c  = (BF*)carve(256 * 2);
    BF* wTq     = (BF*)carve((size_t)384 * 256 * 2);   // [8 kb][384 oc][32]
    BF* wTo     = (BF*)carve((size_t)256 * 256 * 2);   // [8 kb][256 oc][32]
    BF* wt9_0   = (BF*)carve(589824 * 2);     // [9 tap][8 kb][256 oc][32]
    BF* wt9_1   = (BF*)carve(589824 * 2);
    BF* wt9_2   = (BF*)carve(589824 * 2);
    BF* wt9_3   = (BF*)carve(589824 * 2);
    BF* cat     = (BF*)carve((size_t)B_N * 1280 * L_N * 2);   // ch-major [a|b|b1|b2|attn]
    // UNION region, 44 MB (disjoint lifetimes):
    //   tmp  U+0      (16MB)  conv chain scratch, dead after m1_cv2
    //   sout U+0      (16MB)  written by samp (after tmp dead), read by outproj
    //   val  U+16MB   (16MB)  qkv -> samp
    //   offb U+32MB   ( 8MB)  qkv -> samp
    //   awb  U+40MB   ( 4MB)  qkv -> softaw -> samp
    char* U = carve((size_t)46137344);
    BF*    tmp  = (BF*)U;
    BF*    sout = (BF*)U;
    BF*    val  = (BF*)(U + 16777216);
    float* offb = (float*)(U + 33554432);
    float* awb  = (float*)(U + 41943040);

    k_detect<<<1, 256, 0, stream>>>((const ushort_t*)d_in[0], flag);
    // x -> cat ch 512..1023 region (per-batch scatter); read by cv1 only
    k_convert_x<<<1024, 256, 0, stream>>>(d_in[0], cat, flag);
    auto conv = [&](const void* src, BF* dst, int n) {
        int grid = (n + 16383) / 16384; if (grid < 1) grid = 1;
        k_convert<<<grid, 256, 0, stream>>>(src, dst, n, flag);
    };
    conv(d_in[9],  qb,     256);
    conv(d_in[11], qb + 256, 64);
    conv(d_in[13], qb + 320, 32);
    conv(d_in[15], outb_c, 256);

    // conv weights: raw [oc][ic] -> fragment-major [kb][oc][32]
    k_rep_w<<<16, 256, 0, stream>>>(d_in[3],  cv1_c, 512, 512,  262144, flag);
    k_rep_w<<<40, 256, 0, stream>>>(d_in[16], cv2_c, 512, 1280, 655360, flag);

    // linear weights: raw [ic][oc] -> fragment-major [kb][oc+roff][32]
    k_zerobf<<<384, 256, 0, stream>>>(wTq, 98304);     // zero all (pad oc 352..383)
    k_tr_mat<<<dim3(8, 8), 256, 0, stream>>>(d_in[8],  wTq, 256, 256, 384, 0,   flag);
    k_tr_mat<<<dim3(2, 8), 256, 0, stream>>>(d_in[10], wTq, 256, 64,  384, 256, flag);
    k_tr_mat<<<dim3(1, 8), 256, 0, stream>>>(d_in[12], wTq, 256, 32,  384, 320, flag);
    k_tr_mat<<<dim3(8, 8), 256, 0, stream>>>(d_in[14], wTo, 256, 256, 256, 0,   flag);
    k_tr_w9<<<256, 256, 0, stream>>>(d_in[4], wt9_0, flag);
    k_tr_w9<<<256, 256, 0, stream>>>(d_in[5], wt9_1, flag);
    k_tr_w9<<<256, 256, 0, stream>>>(d_in[6], wt9_2, flag);
    k_tr_w9<<<256, 256, 0, stream>>>(d_in[7], wt9_3, flag);

    const long CAT = (long)1280 * L_N, C1S = (long)512 * L_N, C0S = (long)256 * L_N;
    // cv1: x (cat ch 512..1023 view, 512ch) -> cat ch 0..511, silu
    k_mconv<1, 64, false><<<dim3(32, 8, 2), 512, 0, stream>>>(
        cat + 2 * C0S, CAT, 0, 512, cv1_c, 512, nullptr, 512, 0,
        cat, nullptr, CAT, nullptr, nullptr, nullptr, nullptr);
    // m0_cv1: b (cat ch 256..511) -> tmp
    k_mconv<9, 32, false><<<dim3(32, 8, 1), 512, 0, stream>>>(
        cat + C0S, CAT, 0, 256, wt9_0, 256, nullptr, 256, 0,
        tmp, nullptr, C0S, nullptr, nullptr, nullptr, nullptr);
    // m0_cv2: tmp -> b1 (cat ch 512..767; x region now dead)
    k_mconv<9, 32, false><<<dim3(32, 8, 1), 512, 0, stream>>>(
        tmp, C0S, 0, 256, wt9_1, 256, nullptr, 256, 0,
        cat + 2 * C0S, nullptr, CAT, nullptr, nullptr, nullptr, nullptr);
    // m1_cv1: b1 -> tmp
    k_mconv<9, 32, false><<<dim3(32, 8, 1), 512, 0, stream>>>(
        cat + 2 * C0S, CAT, 0, 256, wt9_2, 256, nullptr, 256, 0,
        tmp, nullptr, C0S, nullptr, nullptr, nullptr, nullptr);
    // m1_cv2: tmp -> b2 (cat ch 768..1023)
    k_mconv<9, 32, false><<<dim3(32, 8, 1), 512, 0, stream>>>(
        tmp, C0S, 0, 256, wt9_3, 256, nullptr, 256, 0,
        cat + 3 * C0S, nullptr, CAT, nullptr, nullptr, nullptr, nullptr);
    // qkv: b2 -> val / offb / awb  (352 real cols, padded to 384)
    k_mconv<1, 64, false><<<dim3(32, 8, 2), 512, 0, stream>>>(
        cat + 3 * C0S, CAT, 0, 256, wTq, 384, qb, 384, 2,
        nullptr, nullptr, 0, nullptr, val, offb, awb);
    // softmax the 4 attn-weight logits per (b,l,h) in place
    k_softaw<<<1024, 256, 0, stream>>>(awb, B_N * L_N * 8);
    // sampler (tmp dead -> sout reuses U+0)
    k_samp<<<dim3(8192), 256, 0, stream>>>(d_in[1], flag, offb, awb, val, sout);
    // outproj: sout (px-major [px][256]) -> cat ch 1024..1279, +bias, no act
    k_mconv<1, 64, true><<<dim3(32, 8, 1), 512, 0, stream>>>(
        sout, (long)L_N * 256, 256, 256, wTo, 256, outb_c, 256, 3,
        cat + 4 * C0S, nullptr, CAT, nullptr, nullptr, nullptr, nullptr);
    // cv2: cat (1280ch) -> out (512ch), silu, dtype per flag
    k_mconv<1, 64, false><<<dim3(32, 8, 2), 512, 0, stream>>>(
        cat, CAT, 0, 1280, cv2_c, 512, nullptr, 512, 1,
        (BF*)d_out, (float*)d_out, C1S, flag, nullptr, nullptr, nullptr);
}

// Round 11
// 728.021 us; speedup vs baseline: 1.3815x; 1.0519x over previous
//
#include <hip/hip_runtime.h>
#include <hip/hip_bf16.h>

typedef __hip_bfloat16 BF;
typedef unsigned short ushort_t;
typedef __attribute__((ext_vector_type(8))) short short8;
typedef __attribute__((ext_vector_type(4))) short short4v;
typedef __attribute__((ext_vector_type(4))) float f32x4;

#define B_N 8
#define L_N 4096

__device__ __forceinline__ float b2f(BF v){ return __bfloat162float(v); }
__device__ __forceinline__ BF f2b(float v){ return __float2bfloat16(v); }
__device__ __forceinline__ float siluf(float x){ return x / (1.0f + __expf(-x)); }
__device__ __forceinline__ float s2f(short s){ return __uint_as_float(((unsigned)(ushort_t)s) << 16); }
__device__ __forceinline__ short pks(float v){ BF e = f2b(v); return *(short*)&e; }

// load element idx from raw buffer that is fp32 (flagv=1) or bf16 (0); scrub NaN/Inf
__device__ __forceinline__ float load_raw(const void* src, long idx, int fp32)
{
    if (fp32) {
        float v = ((const float*)src)[idx];
        unsigned u = __float_as_uint(v);
        if ((u & 0x7F800000u) == 0x7F800000u) v = 0.f;
        return v;
    } else {
        ushort_t v = ((const ushort_t*)src)[idx];
        if (((v >> 7) & 0xFF) == 0xFF) v = 0;
        unsigned u = ((unsigned)v) << 16;
        return __uint_as_float(u);
    }
}

// -------- dtype detector: count bf16-NaN/Inf exponent patterns ----------
__global__ __launch_bounds__(256) void k_detect(const ushort_t* __restrict__ x,
                                                int* __restrict__ flag)
{
    __shared__ int cnt[256];
    int t = threadIdx.x;
    int c = 0;
    for (int i = t; i < 65536; i += 256) {
        ushort_t v = x[i];
        if (((v >> 7) & 0xFF) == 0xFF) c++;
    }
    cnt[t] = c;
    __syncthreads();
    for (int s = 128; s > 0; s >>= 1) {
        if (t < s) cnt[t] += cnt[t + s];
        __syncthreads();
    }
    if (t == 0) flag[0] = (cnt[0] > 4) ? 1 : 0;  // 1 => source data is fp32
}

// -------- normalize a float input into clean bf16 -----------------------
__global__ __launch_bounds__(256) void k_convert(const void* __restrict__ src,
                                                 BF* __restrict__ dst, int n,
                                                 const int* __restrict__ flag)
{
    int fp32 = flag[0];
    int i = blockIdx.x * 256 + threadIdx.x;
    int stride = gridDim.x * 256;
    for (; i < n; i += stride) dst[i] = f2b(load_raw(src, i, fp32));
}

// -------- convert x (B,512,L) into cat ch512..1023 region per batch -----
__global__ __launch_bounds__(256) void k_convert_x(const void* __restrict__ src,
                                                   BF* __restrict__ cat,
                                                   const int* __restrict__ flag)
{
    int fp32 = flag[0];
    const long PB = (long)512 * L_N;          // 2,097,152 elems per batch
    const long CAT = (long)1280 * L_N;
    long i = (long)blockIdx.x * 256 + threadIdx.x;
    long stride = (long)gridDim.x * 256;
    for (; i < (long)B_N * PB; i += stride) {
        long b = i / PB, j = i - b * PB;
        cat[b * CAT + PB /*ch512 offset = 512*L_N*/ + j] = f2b(load_raw(src, i, fp32));
    }
}

// ---- zero-fill bf16 region ---------------------------------------------
__global__ __launch_bounds__(256) void k_zerobf(BF* __restrict__ p, int n)
{
    int i = blockIdx.x * 256 + threadIdx.x;
    if (i < n) p[i] = f2b(0.f);
}

// ---- matrix transpose+convert into FRAGMENT-MAJOR weight layout:
//      raw in[r=ic][c=oc] -> out[((ic>>5)*opitch + oc+roff)*32 + (ic&31)]
//      (wave wload then reads 1KB contiguous: oc -> +64B, kg -> +16B)
__global__ __launch_bounds__(256) void k_tr_mat(const void* __restrict__ in,
                                                BF* __restrict__ out,
                                                int rows, int cols, int opitch, int roff,
                                                const int* __restrict__ flag)
{
    __shared__ BF tile[32][33];
    int fp32 = flag[0];
    int c0 = blockIdx.x * 32, r0 = blockIdx.y * 32;
    int tx = threadIdx.x & 31, ty = threadIdx.x >> 5;
#pragma unroll
    for (int i = 0; i < 4; i++) {
        int r = r0 + ty + i * 8, c = c0 + tx;
        tile[ty + i * 8][tx] = (r < rows && c < cols) ? f2b(load_raw(in, (long)r * cols + c, fp32))
                                                      : f2b(0.f);
    }
    __syncthreads();
#pragma unroll
    for (int i = 0; i < 4; i++) {
        int c = c0 + ty + i * 8, r = r0 + tx;
        if (c < cols && r < rows)
            out[(((long)(r >> 5) * opitch + (c + roff)) << 5) + (r & 31)] = tile[tx][ty + i * 8];
    }
}

// ---- conv weight repack: raw w[oc][ic] -> out[(ic>>5)*ocn + oc][ic&31]
__global__ __launch_bounds__(256) void k_rep_w(const void* __restrict__ in,
                                               BF* __restrict__ out,
                                               int ocn, int cin, int n,
                                               const int* __restrict__ flag)
{
    int fp32 = flag[0];
    int i = blockIdx.x * 256 + threadIdx.x;
    int stride = gridDim.x * 256;
    for (; i < n; i += stride) {
        int oc = i / cin, ic = i - oc * cin;
        out[(((long)(ic >> 5) * ocn + oc) << 5) + (ic & 31)] = f2b(load_raw(in, i, fp32));
    }
}

// ---- conv weight transpose: raw w[oc][ic][9] -> wt[tap][ic>>5][oc][ic&31]
__global__ __launch_bounds__(256) void k_tr_w9(const void* __restrict__ w,
                                               BF* __restrict__ wt,
                                               const int* __restrict__ flag)
{
    int fp32 = flag[0];
    int idx = blockIdx.x * 256 + threadIdx.x;      // 65536 = oc*256+ic
    int oc = idx >> 8, ic = idx & 255;
#pragma unroll
    for (int tap = 0; tap < 9; tap++)
        wt[((((long)tap * 8 + (ic >> 5)) * 256 + oc) << 5) + (ic & 31)]
            = f2b(load_raw(w, (long)idx * 9 + tap, fp32));
}

// ================= universal MFMA implicit-GEMM conv ====================
// Round-8 proven structure: ch-major activations [cin][L], block 128px x
// (64*NFR)oc, 8 waves (2M x 4N), wave 64px x (16*NFR)oc, KC-chunked dbuf
// LDS, single __syncthreads per chunk, weight-tap double-buffering,
// fragment-major weights [tap][kb][oc][32] (coalesced wave reads).
// NFR=4: 256oc blocks (cv1/qkv/cv2).  NFR=2: 128oc blocks + grid.z x2 ->
// 512 blocks = 2 blocks/CU for coutp=256 layers (3x3s, outproj): fills
// the barrier/staging stalls with a second block's waves.
// modes: 0 = silu->bf16 ch-major | 1 = silu->bf16/fp32 by flag (cv2)
//        2 = qkv epilogue        | 3 = +bias, no act, bf16 ch-major
template<int TAPS, int KC, bool PXM, int NFR>
__global__ __launch_bounds__(512, 2) void k_mconv(
    const BF* __restrict__ in, long in_bstride, int ipitch, int cin,
    const BF* __restrict__ wT, int ocp,
    const BF* __restrict__ bias, int coutp, int mode,
    BF* __restrict__ outb, float* __restrict__ outf, long out_bstride,
    const int* __restrict__ flag,
    BF* __restrict__ valp, float* __restrict__ offb, float* __restrict__ awb)
{
    constexpr int NROWS = (TAPS == 9) ? 257 : 128;
    constexpr int PITCH = KC + 8;          // 40 / 72 shorts, b128-aligned rows
    constexpr int NKS   = KC / 32;
    __shared__ short ldsA[2][NROWS * PITCH];

    const int t    = threadIdx.x;
    const int lane = t & 63;
    const int wv   = t >> 6;             // 0..7
    const int ln   = lane & 15;
    const int kg   = lane >> 4;          // 0..3
    const int wr   = wv >> 2;            // 0..1  (M half)
    const int wc   = wv & 3;             // 0..3  (N quarter)
    const int px0  = blockIdx.x * 128;
    const int b    = blockIdx.y;
    const int nbase = blockIdx.z * (NFR * 64) + wc * (NFR * 16);
    const bool active = (nbase < coutp);
    const BF* inb = in + (long)b * in_bstride;
    const int NKB = cin >> 5;            // 32-ch K-blocks in weight layout

    int icp, seg, srow, scol;
    if (PXM)            { srow = t >> 2; scol = (t & 3) * 16; icp = 0; seg = 0; }
    else if (TAPS == 9) { icp = t & 15; seg = t >> 4; srow = 0; scol = 0; }
    else                { icp = t & 31; seg = t >> 5; srow = 0; scol = 0; }
    const int gp0 = (TAPS == 9) ? (px0 - 64 + seg * 8) : (px0 + seg * 8);
    const bool sval = (TAPS != 9) || (gp0 >= 0 && gp0 < L_N);

    if (TAPS == 9) {                      // zero halo row 256 in BOTH buffers
        if (t < 20)            ((unsigned*)&ldsA[0][256 * PITCH])[t] = 0u;
        if (t >= 64 && t < 84) ((unsigned*)&ldsA[1][256 * PITCH])[t - 64] = 0u;
    }

    f32x4 acc[4][NFR];
#pragma unroll
    for (int mf = 0; mf < 4; mf++)
#pragma unroll
        for (int nf = 0; nf < NFR; nf++) {
            f32x4 z = {0.f, 0.f, 0.f, 0.f};
            acc[mf][nf] = z;
        }

    const int nchunks = cin / KC;
    short8 r0, r1;

    auto load_chunk = [&](int c0) {
        if (PXM) {
            const BF* p = inb + (long)(px0 + srow) * ipitch + c0 + scol;
            r0 = *(const short8*)p;
            r1 = *(const short8*)(p + 8);
        } else {
            if (sval) {
                const BF* p0 = inb + (long)(c0 + icp * 2) * L_N + gp0;
                r0 = *(const short8*)p0;
                r1 = *(const short8*)(p0 + L_N);
            }
        }
    };
    auto write_chunk = [&](int buf) {
        if (PXM) {
            *(short8*)&ldsA[buf][srow * PITCH + scol]     = r0;
            *(short8*)&ldsA[buf][srow * PITCH + scol + 8] = r1;
        } else {
#pragma unroll
            for (int k = 0; k < 8; k++) {
                unsigned pk = sval ? ((unsigned)(ushort_t)r0[k] |
                                     ((unsigned)(ushort_t)r1[k] << 16)) : 0u;
                *(unsigned*)&ldsA[buf][(seg * 8 + k) * PITCH + icp * 2] = pk;
            }
        }
    };

    // fragment-major weight load: wave reads contiguous (coalesced)
    auto wload = [&](int kb, int tap, int nf) -> short8 {
        int oc = nbase + nf * 16 + ln;
        return *(const short8*)(wT + ((((long)tap * NKB + kb) * ocp + oc) << 5) + kg * 8);
    };

    load_chunk(0);
    write_chunk(0);
    __syncthreads();

    for (int ci = 0; ci < nchunks; ++ci) {
        const int cur = ci & 1;
        const int c0 = ci * KC;
        const int kb0 = ci * NKS;
        const bool more = (ci + 1 < nchunks);
        if (more) load_chunk(c0 + KC);          // issue EARLY: hides under MFMA
        __builtin_amdgcn_sched_barrier(0);      // pin prefetch issue before compute
        if (active) {
            short8 bcur[NFR], bnxt[NFR];
#pragma unroll
            for (int nf = 0; nf < NFR; nf++) bcur[nf] = wload(kb0, 0, nf);
#pragma unroll
            for (int ks = 0; ks < NKS; ks++) {
#pragma unroll
                for (int tap = 0; tap < TAPS; ++tap) {
                    const int dy = (TAPS == 9) ? (tap / 3 - 1) : 0;
                    const int dx = (TAPS == 9) ? (tap % 3 - 1) : 0;
                    const bool lastit = (ks == NKS - 1) && (tap == TAPS - 1);
                    if (!lastit) {                  // prefetch next tap's weights
                        const int nks  = (tap == TAPS - 1) ? ks + 1 : ks;
                        const int ntap = (tap == TAPS - 1) ? 0 : tap + 1;
#pragma unroll
                        for (int nf = 0; nf < NFR; nf++) bnxt[nf] = wload(kb0 + nks, ntap, nf);
                    }
                    short8 afr[4];
#pragma unroll
                    for (int mf = 0; mf < 4; mf++) {
                        int ml = wr * 64 + mf * 16 + ln;
                        int row;
                        if (TAPS == 9) {
                            int xs = (ml & 63) + dx;
                            row = (xs >= 0 && xs < 64) ? (ml + dy * 64 + dx + 64) : 256;
                        } else {
                            row = ml;
                        }
                        afr[mf] = *(const short8*)&ldsA[cur][row * PITCH + ks * 32 + kg * 8];
                    }
#pragma unroll
                    for (int mf = 0; mf < 4; mf++)
#pragma unroll
                        for (int nf = 0; nf < NFR; nf++)
                            acc[mf][nf] = __builtin_amdgcn_mfma_f32_16x16x32_bf16(
                                afr[mf], bcur[nf], acc[mf][nf], 0, 0, 0);
                    if (!lastit) {
#pragma unroll
                        for (int nf = 0; nf < NFR; nf++) bcur[nf] = bnxt[nf];
                    }
                }
            }
        }
        if (more) write_chunk(cur ^ 1);         // LDS write into the OTHER buffer
        __syncthreads();                        // single barrier per chunk
    }
    if (!active) return;

    // ---------------- epilogue (8B vector stores, ch-major out) ---------
    const int wf = (mode == 1 && flag) ? flag[0] : 0;
#pragma unroll
    for (int mf = 0; mf < 4; mf++) {
        int px = px0 + wr * 64 + mf * 16 + kg * 4;
#pragma unroll
        for (int nf = 0; nf < NFR; nf++) {
            int oc = nbase + nf * 16 + ln;
            f32x4 a = acc[mf][nf];
            if (mode == 0 || mode == 1) {
                a.x = siluf(a.x); a.y = siluf(a.y); a.z = siluf(a.z); a.w = siluf(a.w);
                if (wf) {
                    float* dst = outf + (long)b * out_bstride + (long)oc * L_N + px;
                    *(f32x4*)dst = a;
                } else {
                    BF* dst = outb + (long)b * out_bstride + (long)oc * L_N + px;
                    short4v sv;
                    sv.x = pks(a.x); sv.y = pks(a.y); sv.z = pks(a.z); sv.w = pks(a.w);
                    *(short4v*)dst = sv;
                }
            } else if (mode == 3) {
                float bs = b2f(bias[oc]);
                BF* dst = outb + (long)b * out_bstride + (long)oc * L_N + px;
                short4v sv;
                sv.x = pks(a.x + bs); sv.y = pks(a.y + bs);
                sv.z = pks(a.z + bs); sv.w = pks(a.w + bs);
                *(short4v*)dst = sv;
            } else {  // mode 2: qkv
                if (oc >= 352) continue;
                float bs = b2f(bias[oc]);
                a.x += bs; a.y += bs; a.z += bs; a.w += bs;
                if (oc < 256) {
                    int h = oc >> 5, d = oc & 31;
                    BF* vp = valp + ((long)(b * 8 + h) * L_N + px) * 32 + d;
                    vp[0] = f2b(a.x); vp[32] = f2b(a.y); vp[64] = f2b(a.z); vp[96] = f2b(a.w);
                } else if (oc < 320) {
                    float* op = offb + ((long)b * L_N + px) * 64 + (oc - 256);
                    op[0] = a.x; op[64] = a.y; op[128] = a.z; op[192] = a.w;
                } else {
                    float* ap = awb + ((long)b * L_N + px) * 32 + (oc - 320);
                    ap[0] = a.x; ap[32] = a.y; ap[64] = a.z; ap[96] = a.w;
                }
            }
        }
    }
}

// ---- softmax over the 4 attn-weight logits per (b,l,h), in place -------
// awb layout: [(b*L+l)*8 + h] float4s, contiguous -> trivially coalesced.
__global__ __launch_bounds__(256) void k_softaw(float* __restrict__ awb, int n)
{
    int i = blockIdx.x * 256 + threadIdx.x;
    if (i >= n) return;
    f32x4 a = *(f32x4*)(awb + (long)i * 4);
    float m = fmaxf(fmaxf(a.x, a.y), fmaxf(a.z, a.w));
    float e0 = __expf(a.x - m), e1 = __expf(a.y - m);
    float e2 = __expf(a.z - m), e3 = __expf(a.w - m);
    float inv = 1.f / (e0 + e1 + e2 + e3);
    f32x4 r; r.x = e0 * inv; r.y = e1 * inv; r.z = e2 * inv; r.w = e3 * inv;
    *(f32x4*)(awb + (long)i * 4) = r;
}

// ---------------- deformable sampler ------------------------------------
// 8 lanes per (b,l,h) group; each lane handles 4 consecutive d via 8B
// short4v gathers.  Softmax pre-applied by k_softaw (awb holds weights).
__global__ __launch_bounds__(256) void k_samp(const void* __restrict__ rb_raw,
                                              const int* __restrict__ flag,
                                              const float* __restrict__ offb,
                                              const float* __restrict__ awb,
                                              const BF* __restrict__ val,
                                              BF* __restrict__ sout)
{
    int fp32 = flag[0];
    int t = threadIdx.x;
    int g = blockIdx.x * 32 + (t >> 3);   // group = (b,l,h)
    int dq = t & 7;                        // handles d = dq*4 .. dq*4+3
    int l = g & (L_N - 1);
    int h = (g >> 12) & 7;
    int b = g >> 15;
    const float* op = offb + ((long)b * L_N + l) * 64 + h * 8;
    const float* ap = awb + ((long)b * L_N + l) * 32 + h * 4;   // normalized
    float rx = load_raw(rb_raw, ((long)b * L_N + l) * 2 + 0, fp32) * 64.f - 0.5f;
    float ry = load_raw(rb_raw, ((long)b * L_N + l) * 2 + 1, fp32) * 64.f - 0.5f;
    const BF* vb = val + ((long)(b * 8 + h) * L_N) * 32 + dq * 4;
    float o0 = 0.f, o1 = 0.f, o2 = 0.f, o3 = 0.f;
    short4v z4 = {0, 0, 0, 0};
#pragma unroll
    for (int p = 0; p < 4; p++) {
        float aw = ap[p];
        float gx = rx + op[p * 2 + 0];
        float gy = ry + op[p * 2 + 1];
        float fx = floorf(gx), fy = floorf(gy);
        int x0 = (int)fx, y0 = (int)fy;
        float wx1 = gx - fx, wy1 = gy - fy;
        float wx0 = 1.f - wx1, wy0 = 1.f - wy1;
        float w00 = aw * wx0 * wy0, w10 = aw * wx1 * wy0;
        float w01 = aw * wx0 * wy1, w11 = aw * wx1 * wy1;
        bool vx0 = ((unsigned)x0 < 64u), vx1 = ((unsigned)(x0 + 1) < 64u);
        bool vy0 = ((unsigned)y0 < 64u), vy1 = ((unsigned)(y0 + 1) < 64u);
        const BF* pr0 = vb + (long)(y0 * 64 + x0) * 32;
        short4v v00 = (vx0 && vy0) ? *(const short4v*)(pr0)            : z4;
        short4v v10 = (vx1 && vy0) ? *(const short4v*)(pr0 + 32)       : z4;
        short4v v01 = (vx0 && vy1) ? *(const short4v*)(pr0 + 64 * 32)  : z4;
        short4v v11 = (vx1 && vy1) ? *(const short4v*)(pr0 + 65 * 32)  : z4;
        o0 += s2f(v00.x) * w00 + s2f(v10.x) * w10 + s2f(v01.x) * w01 + s2f(v11.x) * w11;
        o1 += s2f(v00.y) * w00 + s2f(v10.y) * w10 + s2f(v01.y) * w01 + s2f(v11.y) * w11;
        o2 += s2f(v00.z) * w00 + s2f(v10.z) * w10 + s2f(v01.z) * w01 + s2f(v11.z) * w11;
        o3 += s2f(v00.w) * w00 + s2f(v10.w) * w10 + s2f(v01.w) * w01 + s2f(v11.w) * w11;
    }
    short4v sv;
    sv.x = pks(o0); sv.y = pks(o1); sv.z = pks(o2); sv.w = pks(o3);
    *(short4v*)(sout + ((long)b * L_N + l) * 256 + h * 32 + dq * 4) = sv;
}

extern "C" void kernel_launch(void* const* d_in, const int* in_sizes, int n_in,
                              void* d_out, int out_size, void* d_ws, size_t ws_size,
                              hipStream_t stream)
{
    (void)in_sizes; (void)n_in; (void)out_size; (void)ws_size;
    char* ws = (char*)d_ws;
    size_t woff = 0;
    auto carve = [&](size_t bytes) -> char* {
        char* p = ws + woff;
        woff += (bytes + 255) & ~(size_t)255;
        return p;
    };
    int* flag   = (int*)carve(256);
    BF* cv1_c   = (BF*)carve(262144 * 2);     // [16 kb][512 oc][32]
    BF* cv2_c   = (BF*)carve(655360 * 2);     // [40 kb][512 oc][32]
    BF* qb      = (BF*)carve(384 * 2);        // vproj_b | off_b | aw_b
    BF* outb_c  = (BF*)carve(256 * 2);
    BF* wTq     = (BF*)carve((size_t)384 * 256 * 2);   // [8 kb][384 oc][32]
    BF* wTo     = (BF*)carve((size_t)256 * 256 * 2);   // [8 kb][256 oc][32]
    BF* wt9_0   = (BF*)carve(589824 * 2);     // [9 tap][8 kb][256 oc][32]
    BF* wt9_1   = (BF*)carve(589824 * 2);
    BF* wt9_2   = (BF*)carve(589824 * 2);
    BF* wt9_3   = (BF*)carve(589824 * 2);
    BF* cat     = (BF*)carve((size_t)B_N * 1280 * L_N * 2);   // ch-major [a|b|b1|b2|attn]
    // UNION region, 44 MB (disjoint lifetimes):
    //   tmp  U+0      (16MB)  conv chain scratch, dead after m1_cv2
    //   sout U+0      (16MB)  written by samp (after tmp dead), read by outproj
    //   val  U+16MB   (16MB)  qkv -> samp
    //   offb U+32MB   ( 8MB)  qkv -> samp
    //   awb  U+40MB   ( 4MB)  qkv -> softaw -> samp
    char* U = carve((size_t)46137344);
    BF*    tmp  = (BF*)U;
    BF*    sout = (BF*)U;
    BF*    val  = (BF*)(U + 16777216);
    float* offb = (float*)(U + 33554432);
    float* awb  = (float*)(U + 41943040);

    k_detect<<<1, 256, 0, stream>>>((const ushort_t*)d_in[0], flag);
    // x -> cat ch 512..1023 region (per-batch scatter); read by cv1 only
    k_convert_x<<<1024, 256, 0, stream>>>(d_in[0], cat, flag);
    auto conv = [&](const void* src, BF* dst, int n) {
        int grid = (n + 16383) / 16384; if (grid < 1) grid = 1;
        k_convert<<<grid, 256, 0, stream>>>(src, dst, n, flag);
    };
    conv(d_in[9],  qb,     256);
    conv(d_in[11], qb + 256, 64);
    conv(d_in[13], qb + 320, 32);
    conv(d_in[15], outb_c, 256);

    // conv weights: raw [oc][ic] -> fragment-major [kb][oc][32]
    k_rep_w<<<16, 256, 0, stream>>>(d_in[3],  cv1_c, 512, 512,  262144, flag);
    k_rep_w<<<40, 256, 0, stream>>>(d_in[16], cv2_c, 512, 1280, 655360, flag);

    // linear weights: raw [ic][oc] -> fragment-major [kb][oc+roff][32]
    k_zerobf<<<384, 256, 0, stream>>>(wTq, 98304);     // zero all (pad oc 352..383)
    k_tr_mat<<<dim3(8, 8), 256, 0, stream>>>(d_in[8],  wTq, 256, 256, 384, 0,   flag);
    k_tr_mat<<<dim3(2, 8), 256, 0, stream>>>(d_in[10], wTq, 256, 64,  384, 256, flag);
    k_tr_mat<<<dim3(1, 8), 256, 0, stream>>>(d_in[12], wTq, 256, 32,  384, 320, flag);
    k_tr_mat<<<dim3(8, 8), 256, 0, stream>>>(d_in[14], wTo, 256, 256, 256, 0,   flag);
    k_tr_w9<<<256, 256, 0, stream>>>(d_in[4], wt9_0, flag);
    k_tr_w9<<<256, 256, 0, stream>>>(d_in[5], wt9_1, flag);
    k_tr_w9<<<256, 256, 0, stream>>>(d_in[6], wt9_2, flag);
    k_tr_w9<<<256, 256, 0, stream>>>(d_in[7], wt9_3, flag);

    const long CAT = (long)1280 * L_N, C1S = (long)512 * L_N, C0S = (long)256 * L_N;
    // cv1: x (cat ch 512..1023 view, 512ch) -> cat ch 0..511, silu
    k_mconv<1, 64, false, 4><<<dim3(32, 8, 2), 512, 0, stream>>>(
        cat + 2 * C0S, CAT, 0, 512, cv1_c, 512, nullptr, 512, 0,
        cat, nullptr, CAT, nullptr, nullptr, nullptr, nullptr);
    // m0_cv1: b (cat ch 256..511) -> tmp  [NFR=2, z=2 -> 2 blocks/CU]
    k_mconv<9, 32, false, 2><<<dim3(32, 8, 2), 512, 0, stream>>>(
        cat + C0S, CAT, 0, 256, wt9_0, 256, nullptr, 256, 0,
        tmp, nullptr, C0S, nullptr, nullptr, nullptr, nullptr);
    // m0_cv2: tmp -> b1 (cat ch 512..767; x region now dead)
    k_mconv<9, 32, false, 2><<<dim3(32, 8, 2), 512, 0, stream>>>(
        tmp, C0S, 0, 256, wt9_1, 256, nullptr, 256, 0,
        cat + 2 * C0S, nullptr, CAT, nullptr, nullptr, nullptr, nullptr);
    // m1_cv1: b1 -> tmp
    k_mconv<9, 32, false, 2><<<dim3(32, 8, 2), 512, 0, stream>>>(
        cat + 2 * C0S, CAT, 0, 256, wt9_2, 256, nullptr, 256, 0,
        tmp, nullptr, C0S, nullptr, nullptr, nullptr, nullptr);
    // m1_cv2: tmp -> b2 (cat ch 768..1023)
    k_mconv<9, 32, false, 2><<<dim3(32, 8, 2), 512, 0, stream>>>(
        tmp, C0S, 0, 256, wt9_3, 256, nullptr, 256, 0,
        cat + 3 * C0S, nullptr, CAT, nullptr, nullptr, nullptr, nullptr);
    // qkv: b2 -> val / offb / awb  (352 real cols, padded to 384)
    k_mconv<1, 64, false, 4><<<dim3(32, 8, 2), 512, 0, stream>>>(
        cat + 3 * C0S, CAT, 0, 256, wTq, 384, qb, 384, 2,
        nullptr, nullptr, 0, nullptr, val, offb, awb);
    // softmax the 4 attn-weight logits per (b,l,h) in place
    k_softaw<<<1024, 256, 0, stream>>>(awb, B_N * L_N * 8);
    // sampler (tmp dead -> sout reuses U+0)
    k_samp<<<dim3(8192), 256, 0, stream>>>(d_in[1], flag, offb, awb, val, sout);
    // outproj: sout (px-major [px][256]) -> cat ch 1024..1279, +bias, no act
    k_mconv<1, 64, true, 2><<<dim3(32, 8, 2), 512, 0, stream>>>(
        sout, (long)L_N * 256, 256, 256, wTo, 256, outb_c, 256, 3,
        cat + 4 * C0S, nullptr, CAT, nullptr, nullptr, nullptr, nullptr);
    // cv2: cat (1280ch) -> out (512ch), silu, dtype per flag
    k_mconv<1, 64, false, 4><<<dim3(32, 8, 2), 512, 0, stream>>>(
        cat, CAT, 0, 1280, cv2_c, 512, nullptr, 512, 1,
        (BF*)d_out, (float*)d_out, C1S, flag, nullptr, nullptr, nullptr);
}